// Round 6
// baseline (1582.955 us; speedup 1.0000x reference)
//
#include <hip/hip_runtime.h>
#include <math.h>

#define NN 100000
#define F 64
#define NC 47
#define SCAN_BLK 1024   // elements per scan1 block (256 thr x 4)
#define BIN 128         // rows per conv block
#define ROWSTRIDE 65    // LDS acc row stride (rotates banks per row)

// ---------------------------------------------------------------------------
// Edge dtype handling: harness may deliver edge_index as int32 or int64.
// ---------------------------------------------------------------------------
__global__ void detect_kernel(const void* __restrict__ ei, int* __restrict__ flag) {
    const int* e32 = (const int*)ei;
    int i = threadIdx.x;                 // 64 threads
    int v = e32[2 * i + 1];
    unsigned long long ball = __ballot(v == 0);
    if (i == 0) *flag = (ball == ~0ULL) ? 1 : 0;  // all-zero odd words => int64
}

__global__ void convert_kernel(const void* __restrict__ ei, const int* __restrict__ flag,
                               int* __restrict__ out, int n2e) {
    int i = blockIdx.x * blockDim.x + threadIdx.x;
    if (i >= n2e) return;
    if (*flag)
        out[i] = (int)((const long long*)ei)[i];
    else
        out[i] = ((const int*)ei)[i];
}

// ---------------------------------------------------------------------------
// degree + dinv
// ---------------------------------------------------------------------------
__global__ void deg_kernel(const int* __restrict__ dst, int* __restrict__ deg, int E) {
    int e = blockIdx.x * blockDim.x + threadIdx.x;
    if (e < E) atomicAdd(&deg[dst[e]], 1);
}

__global__ void dinv_kernel(const int* __restrict__ deg, float* __restrict__ dinv, int n) {
    int i = blockIdx.x * blockDim.x + threadIdx.x;
    if (i < n) {
        int d = deg[i];
        dinv[i] = (d > 0) ? rsqrtf((float)d) : 0.0f;
    }
}

// ---------------------------------------------------------------------------
// exclusive scan of deg -> rowptr (proven round-4 machinery)
// ---------------------------------------------------------------------------
__global__ __launch_bounds__(256) void scan1_kernel(const int* __restrict__ deg,
                                                    int* __restrict__ excl,
                                                    int* __restrict__ bsum, int n) {
    __shared__ int lds[256];
    int t = threadIdx.x;
    int base = blockIdx.x * SCAN_BLK + t * 4;
    int v0 = (base + 0 < n) ? deg[base + 0] : 0;
    int v1 = (base + 1 < n) ? deg[base + 1] : 0;
    int v2 = (base + 2 < n) ? deg[base + 2] : 0;
    int v3 = (base + 3 < n) ? deg[base + 3] : 0;
    int s = v0 + v1 + v2 + v3;
    lds[t] = s;
    __syncthreads();
    for (int off = 1; off < 256; off <<= 1) {
        int a = (t >= off) ? lds[t - off] : 0;
        __syncthreads();
        lds[t] += a;
        __syncthreads();
    }
    int inc = lds[t];
    int exc = inc - s;
    if (t == 255) bsum[blockIdx.x] = inc;
    if (base + 0 < n) excl[base + 0] = exc;
    if (base + 1 < n) excl[base + 1] = exc + v0;
    if (base + 2 < n) excl[base + 2] = exc + v0 + v1;
    if (base + 3 < n) excl[base + 3] = exc + v0 + v1 + v2;
}

__global__ __launch_bounds__(256) void scan2_kernel(int* __restrict__ bsum, int nb) {
    __shared__ int lds[256];
    int t = threadIdx.x;
    int v = (t < nb) ? bsum[t] : 0;
    lds[t] = v;
    __syncthreads();
    for (int off = 1; off < 256; off <<= 1) {
        int a = (t >= off) ? lds[t - off] : 0;
        __syncthreads();
        lds[t] += a;
        __syncthreads();
    }
    if (t < nb) bsum[t] = lds[t] - v;   // exclusive
}

__global__ void scan3_kernel(const int* __restrict__ excl, const int* __restrict__ bsum,
                             int* __restrict__ rowptr, int* __restrict__ cursor,
                             int n, int E) {
    int i = blockIdx.x * blockDim.x + threadIdx.x;
    if (i >= n) return;
    int r = excl[i] + bsum[i >> 10];
    rowptr[i] = r;
    cursor[i] = r;
    if (i == 0) rowptr[n] = E;
}

// ---------------------------------------------------------------------------
// counting-sort scatter (proven round-4 kernel; payload now packs dst&127
// into spare bits of .x: src(17b) | (dst&127)<<17.  .y = norm bits)
// ---------------------------------------------------------------------------
__global__ void scatter_kernel(const int* __restrict__ src, const int* __restrict__ dst,
                               const float* __restrict__ dinv, int* __restrict__ cursor,
                               int2* __restrict__ esort, int E) {
    int e = blockIdx.x * blockDim.x + threadIdx.x;
    if (e >= E) return;
    int s = src[e];
    int d = dst[e];
    float nm = dinv[s] * dinv[d];
    int pos = atomicAdd(&cursor[d], 1);
    esort[pos] = make_int2(s | ((d & 127) << 17), __float_as_int(nm));
}

// ---------------------------------------------------------------------------
// conv: one block per 128-row bin of the dst-sorted CSR. LDS accumulator
// (stride 65 rotates banks per row). 64 lanes = 4 edges x 16 float4 slices;
// float4 gathers give 4x fewer VMEM instructions than the per-float conv_csr.
// Output is raw conv result (pre-relu), norm applied per edge (round-4 math).
// ---------------------------------------------------------------------------
__global__ __launch_bounds__(256) void conv_bin_kernel(const float4* __restrict__ x4,
                                                       const int* __restrict__ rowptr,
                                                       const int2* __restrict__ esort,
                                                       float* __restrict__ out) {
    __shared__ float acc[BIN * ROWSTRIDE];
    int b = blockIdx.x, t = threadIdx.x;
    for (int i = t; i < BIN * ROWSTRIDE; i += 256) acc[i] = 0.0f;
    __syncthreads();
    int row_lo = b * BIN;
    int row_hi = row_lo + BIN;
    if (row_hi > NN) row_hi = NN;
    int beg = rowptr[row_lo];
    int end = rowptr[row_hi];
    int wid = t >> 6, lane = t & 63, es = lane >> 4, f4 = lane & 15;
    for (int base = beg + wid * 64; base < end; base += 256) {
        int m = end - base;
        if (m > 64) m = 64;
        int2 pk = (lane < m) ? esort[base + lane] : make_int2(0, 0);
#pragma unroll 4
        for (int k = 0; k < 16; ++k) {
            int idx = 4 * k + es;
            if (idx < m) {
                int sx   = __shfl(pk.x, idx, 64);
                float nm = __int_as_float(__shfl(pk.y, idx, 64));
                int s  = sx & 0x1FFFF;
                int dl = (sx >> 17) & 127;
                float4 v = x4[(size_t)s * 16 + f4];
                float* ap = &acc[dl * ROWSTRIDE + f4 * 4];
                atomicAdd(ap + 0, v.x * nm);
                atomicAdd(ap + 1, v.y * nm);
                atomicAdd(ap + 2, v.z * nm);
                atomicAdd(ap + 3, v.w * nm);
            }
        }
    }
    __syncthreads();
    for (int i = t; i < BIN * 64; i += 256) {
        int r = i >> 6, f = i & 63;
        int gr = row_lo + r;
        if (gr < NN) out[(size_t)gr * 64 + f] = acc[r * ROWSTRIDE + f];
    }
}

// ---------------------------------------------------------------------------
// Register-tiled lin kernels (round-4 proven versions, verbatim).
// ---------------------------------------------------------------------------
__device__ __forceinline__ float4 relu4(float4 v) {
    v.x = fmaxf(v.x, 0.0f); v.y = fmaxf(v.y, 0.0f);
    v.z = fmaxf(v.z, 0.0f); v.w = fmaxf(v.w, 0.0f);
    return v;
}

__global__ __launch_bounds__(256) void lin1_kernel(const float* __restrict__ h,
                                                   const float* __restrict__ W1,
                                                   const float* __restrict__ b1,
                                                   float* __restrict__ out, int n) {
    __shared__ float wt[64 * 64];
    __shared__ float ht[64 * 64];
    int t = threadIdx.x;
    for (int i = t; i < 64 * 64; i += 256) {
        int k = i >> 6, c = i & 63;
        int kq = k >> 2, slot = kq ^ (c & 7);
        wt[c * 64 + slot * 4 + (k & 3)] = W1[i];
    }
    int row0 = blockIdx.x * 64;
    const float4* h4 = (const float4*)h;
    float4* ht4 = (float4*)ht;
#pragma unroll
    for (int j = 0; j < 4; ++j) {
        int flat = t + 256 * j;
        int r = flat >> 4;
        int kq = flat & 15;
        int gr = row0 + r;
        float4 v = (gr < n) ? relu4(h4[(size_t)gr * 16 + kq])
                            : make_float4(0.f, 0.f, 0.f, 0.f);
        ht4[r * 16 + (kq ^ ((r >> 2) & 7))] = v;
    }
    __syncthreads();
    const float4* wt4 = (const float4*)wt;
    const float4* ht4c = (const float4*)ht;

    int tx = t & 15, ty = t >> 4;
    float acc[4][4] = {};
#pragma unroll 2
    for (int kq = 0; kq < 16; ++kq) {
        int wslot = kq ^ (tx & 7);
        float4 b0 = wt4[(tx +  0) * 16 + wslot];
        float4 b1v = wt4[(tx + 16) * 16 + wslot];
        float4 b2v = wt4[(tx + 32) * 16 + wslot];
        float4 b3v = wt4[(tx + 48) * 16 + wslot];
        int aslot = kq ^ (ty & 7);
#pragma unroll
        for (int i = 0; i < 4; ++i) {
            float4 a = ht4c[(4 * ty + i) * 16 + aslot];
            acc[i][0] = fmaf(a.x, b0.x,  fmaf(a.y, b0.y,  fmaf(a.z, b0.z,  fmaf(a.w, b0.w,  acc[i][0]))));
            acc[i][1] = fmaf(a.x, b1v.x, fmaf(a.y, b1v.y, fmaf(a.z, b1v.z, fmaf(a.w, b1v.w, acc[i][1]))));
            acc[i][2] = fmaf(a.x, b2v.x, fmaf(a.y, b2v.y, fmaf(a.z, b2v.z, fmaf(a.w, b2v.w, acc[i][2]))));
            acc[i][3] = fmaf(a.x, b3v.x, fmaf(a.y, b3v.y, fmaf(a.z, b3v.z, fmaf(a.w, b3v.w, acc[i][3]))));
        }
    }
    float bj[4];
#pragma unroll
    for (int g = 0; g < 4; ++g) bj[g] = b1[tx + 16 * g];
    int r0 = row0 + 4 * ty;
#pragma unroll
    for (int i = 0; i < 4; ++i) {
        int r = r0 + i;
        if (r >= n) break;
#pragma unroll
        for (int g = 0; g < 4; ++g)
            out[(size_t)r * 64 + tx + 16 * g] = fmaxf(acc[i][g] + bj[g], 0.0f);
    }
}

__global__ __launch_bounds__(256) void lin2_kernel(const float* __restrict__ h,
                                                   const float* __restrict__ W2,
                                                   const float* __restrict__ b2,
                                                   float* __restrict__ out, int n) {
    __shared__ float wt[64 * 64];   // cols >= 47 zero-padded
    __shared__ float ht[64 * 64];
    int t = threadIdx.x;
    for (int i = t; i < 64 * 64; i += 256) {
        int k = i >> 6, c = i & 63;
        int kq = k >> 2, slot = kq ^ (c & 7);
        wt[c * 64 + slot * 4 + (k & 3)] = (c < NC) ? W2[k * NC + c] : 0.0f;
    }
    int row0 = blockIdx.x * 64;
    const float4* h4 = (const float4*)h;
    float4* ht4 = (float4*)ht;
#pragma unroll
    for (int j = 0; j < 4; ++j) {
        int flat = t + 256 * j;
        int r = flat >> 4;
        int kq = flat & 15;
        int gr = row0 + r;
        float4 v = (gr < n) ? relu4(h4[(size_t)gr * 16 + kq])
                            : make_float4(0.f, 0.f, 0.f, 0.f);
        ht4[r * 16 + (kq ^ ((r >> 2) & 7))] = v;
    }
    __syncthreads();
    const float4* wt4 = (const float4*)wt;
    const float4* ht4c = (const float4*)ht;

    int tx = t & 15, ty = t >> 4;
    float acc[4][4] = {};
#pragma unroll 2
    for (int kq = 0; kq < 16; ++kq) {
        int wslot = kq ^ (tx & 7);
        float4 b0 = wt4[(tx +  0) * 16 + wslot];
        float4 b1v = wt4[(tx + 16) * 16 + wslot];
        float4 b2v = wt4[(tx + 32) * 16 + wslot];
        float4 b3v = wt4[(tx + 48) * 16 + wslot];
        int aslot = kq ^ (ty & 7);
#pragma unroll
        for (int i = 0; i < 4; ++i) {
            float4 a = ht4c[(4 * ty + i) * 16 + aslot];
            acc[i][0] = fmaf(a.x, b0.x,  fmaf(a.y, b0.y,  fmaf(a.z, b0.z,  fmaf(a.w, b0.w,  acc[i][0]))));
            acc[i][1] = fmaf(a.x, b1v.x, fmaf(a.y, b1v.y, fmaf(a.z, b1v.z, fmaf(a.w, b1v.w, acc[i][1]))));
            acc[i][2] = fmaf(a.x, b2v.x, fmaf(a.y, b2v.y, fmaf(a.z, b2v.z, fmaf(a.w, b2v.w, acc[i][2]))));
            acc[i][3] = fmaf(a.x, b3v.x, fmaf(a.y, b3v.y, fmaf(a.z, b3v.z, fmaf(a.w, b3v.w, acc[i][3]))));
        }
    }
    bool vm[4];
    float bj[4];
#pragma unroll
    for (int g = 0; g < 4; ++g) {
        int c = tx + 16 * g;
        vm[g] = (c < NC);
        bj[g] = vm[g] ? b2[c] : 0.0f;
    }
    int r0 = row0 + 4 * ty;
#pragma unroll
    for (int i = 0; i < 4; ++i) {
        int r = r0 + i;
        float v[4];
        float m = -INFINITY;
#pragma unroll
        for (int g = 0; g < 4; ++g) {
            v[g] = acc[i][g] + bj[g];
            if (vm[g]) m = fmaxf(m, v[g]);
        }
#pragma unroll
        for (int off = 8; off > 0; off >>= 1) m = fmaxf(m, __shfl_xor(m, off, 64));
        float s = 0.0f;
#pragma unroll
        for (int g = 0; g < 4; ++g)
            if (vm[g]) s += expf(v[g] - m);
#pragma unroll
        for (int off = 8; off > 0; off >>= 1) s += __shfl_xor(s, off, 64);
        float lse = m + logf(s);
        if (r < n) {
#pragma unroll
            for (int g = 0; g < 4; ++g)
                if (vm[g]) out[(size_t)r * NC + tx + 16 * g] = v[g] - lse;
        }
    }
}

// ---------------------------------------------------------------------------
extern "C" void kernel_launch(void* const* d_in, const int* in_sizes, int n_in,
                              void* d_out, int out_size, void* d_ws, size_t ws_size,
                              hipStream_t stream) {
    const float* x  = (const float*)d_in[0];
    const void*  ei = d_in[1];
    const float* W1 = (const float*)d_in[2];
    const float* b1 = (const float*)d_in[3];
    const float* W2 = (const float*)d_in[4];
    const float* b2 = (const float*)d_in[5];
    float* out = (float*)d_out;

    const int E = in_sizes[1] / 2;
    const int n2e = in_sizes[1];
    const int NB = (NN + SCAN_BLK - 1) / SCAN_BLK;   // 98 <= 256

    // workspace carve-out (256B aligned) — identical footprint to round 4
    char* ws = (char*)d_ws;
    size_t off = 0;
    auto alloc = [&](size_t bytes) -> void* {
        void* p = ws + off;
        off = (off + bytes + 255) & ~(size_t)255;
        return p;
    };
    int*   flag   = (int*)  alloc(4);
    int*   deg    = (int*)  alloc((size_t)NN * 4);
    float* dinv   = (float*)alloc((size_t)NN * 4);
    int*   e32    = (int*)  alloc((size_t)n2e * 4);        // src32 | dst32
    int*   excl   = (int*)  alloc((size_t)NN * 4);
    int*   bsum   = (int*)  alloc(256 * 4);
    int*   rowptr = (int*)  alloc((size_t)(NN + 1) * 4);
    int*   cursor = (int*)  alloc((size_t)NN * 4);
    int2*  esort  = (int2*) alloc((size_t)E * 8);
    float* bufA   = (float*)alloc((size_t)NN * F * 4);
    float* bufB   = (float*)alloc((size_t)NN * F * 4);
    int* src32 = e32;
    int* dst32 = e32 + E;

    hipMemsetAsync(deg, 0, (size_t)NN * 4, stream);

    detect_kernel<<<1, 64, 0, stream>>>(ei, flag);
    convert_kernel<<<(n2e + 255) / 256, 256, 0, stream>>>(ei, flag, e32, n2e);

    deg_kernel <<<(E + 255) / 256, 256, 0, stream>>>(dst32, deg, E);
    dinv_kernel<<<(NN + 255) / 256, 256, 0, stream>>>(deg, dinv, NN);

    scan1_kernel<<<NB, 256, 0, stream>>>(deg, excl, bsum, NN);
    scan2_kernel<<<1, 256, 0, stream>>>(bsum, NB);
    scan3_kernel<<<(NN + 255) / 256, 256, 0, stream>>>(excl, bsum, rowptr, cursor, NN, E);

    scatter_kernel<<<(E + 255) / 256, 256, 0, stream>>>(src32, dst32, dinv, cursor, esort, E);

    const int conv_blocks = (NN + BIN - 1) / BIN;   // 782
    const int lin_blocks = (NN + 63) / 64;          // 1563

    // conv1: x -> bufA (raw conv sums)
    conv_bin_kernel<<<conv_blocks, 256, 0, stream>>>(
        (const float4*)x, rowptr, esort, bufA);

    // lin1: relu(bufA) @ W1 + b1, relu -> bufB
    lin1_kernel<<<lin_blocks, 256, 0, stream>>>(bufA, W1, b1, bufB, NN);

    // conv2: bufB -> bufA (raw conv sums)
    conv_bin_kernel<<<conv_blocks, 256, 0, stream>>>(
        (const float4*)bufB, rowptr, esort, bufA);

    // lin2 + log_softmax
    lin2_kernel<<<lin_blocks, 256, 0, stream>>>(bufA, W2, b2, out, NN);
}

// Round 7
// 326.154 us; speedup vs baseline: 4.8534x; 4.8534x over previous
//
#include <hip/hip_runtime.h>
#include <math.h>

#define NN 100000
#define F 64
#define NC 47
#define SCAN_BLK 1024   // elements per scan1 block (256 thr x 4)

// ---------------------------------------------------------------------------
// Edge dtype handling: harness may deliver edge_index as int32 or int64.
// ---------------------------------------------------------------------------
__global__ void detect_kernel(const void* __restrict__ ei, int* __restrict__ flag) {
    const int* e32 = (const int*)ei;
    int i = threadIdx.x;                 // 64 threads
    int v = e32[2 * i + 1];
    unsigned long long ball = __ballot(v == 0);
    if (i == 0) *flag = (ball == ~0ULL) ? 1 : 0;  // all-zero odd words => int64
}

__global__ void convert_kernel(const void* __restrict__ ei, const int* __restrict__ flag,
                               int* __restrict__ out, int n2e) {
    int i = blockIdx.x * blockDim.x + threadIdx.x;
    if (i >= n2e) return;
    if (*flag)
        out[i] = (int)((const long long*)ei)[i];
    else
        out[i] = ((const int*)ei)[i];
}

// ---------------------------------------------------------------------------
// degree + dinv
// ---------------------------------------------------------------------------
__global__ void deg_kernel(const int* __restrict__ dst, int* __restrict__ deg, int E) {
    int e = blockIdx.x * blockDim.x + threadIdx.x;
    if (e < E) atomicAdd(&deg[dst[e]], 1);
}

__global__ void dinv_kernel(const int* __restrict__ deg, float* __restrict__ dinv, int n) {
    int i = blockIdx.x * blockDim.x + threadIdx.x;
    if (i < n) {
        int d = deg[i];
        dinv[i] = (d > 0) ? rsqrtf((float)d) : 0.0f;
    }
}

// ---------------------------------------------------------------------------
// exclusive scan of deg -> rowptr (proven round-4 machinery)
// ---------------------------------------------------------------------------
__global__ __launch_bounds__(256) void scan1_kernel(const int* __restrict__ deg,
                                                    int* __restrict__ excl,
                                                    int* __restrict__ bsum, int n) {
    __shared__ int lds[256];
    int t = threadIdx.x;
    int base = blockIdx.x * SCAN_BLK + t * 4;
    int v0 = (base + 0 < n) ? deg[base + 0] : 0;
    int v1 = (base + 1 < n) ? deg[base + 1] : 0;
    int v2 = (base + 2 < n) ? deg[base + 2] : 0;
    int v3 = (base + 3 < n) ? deg[base + 3] : 0;
    int s = v0 + v1 + v2 + v3;
    lds[t] = s;
    __syncthreads();
    for (int off = 1; off < 256; off <<= 1) {
        int a = (t >= off) ? lds[t - off] : 0;
        __syncthreads();
        lds[t] += a;
        __syncthreads();
    }
    int inc = lds[t];
    int exc = inc - s;
    if (t == 255) bsum[blockIdx.x] = inc;
    if (base + 0 < n) excl[base + 0] = exc;
    if (base + 1 < n) excl[base + 1] = exc + v0;
    if (base + 2 < n) excl[base + 2] = exc + v0 + v1;
    if (base + 3 < n) excl[base + 3] = exc + v0 + v1 + v2;
}

__global__ __launch_bounds__(256) void scan2_kernel(int* __restrict__ bsum, int nb) {
    __shared__ int lds[256];
    int t = threadIdx.x;
    int v = (t < nb) ? bsum[t] : 0;
    lds[t] = v;
    __syncthreads();
    for (int off = 1; off < 256; off <<= 1) {
        int a = (t >= off) ? lds[t - off] : 0;
        __syncthreads();
        lds[t] += a;
        __syncthreads();
    }
    if (t < nb) bsum[t] = lds[t] - v;   // exclusive
}

__global__ void scan3_kernel(const int* __restrict__ excl, const int* __restrict__ bsum,
                             int* __restrict__ rowptr, int* __restrict__ cursor,
                             int n, int E) {
    int i = blockIdx.x * blockDim.x + threadIdx.x;
    if (i >= n) return;
    int r = excl[i] + bsum[i >> 10];
    rowptr[i] = r;
    cursor[i] = r;
    if (i == 0) rowptr[n] = E;
}

// ---------------------------------------------------------------------------
// counting-sort scatter (round-4 proven; payload = {src, norm_bits})
// ---------------------------------------------------------------------------
__global__ void scatter_kernel(const int* __restrict__ src, const int* __restrict__ dst,
                               const float* __restrict__ dinv, int* __restrict__ cursor,
                               int2* __restrict__ esort, int E) {
    int e = blockIdx.x * blockDim.x + threadIdx.x;
    if (e >= E) return;
    int s = src[e];
    int d = dst[e];
    float nm = dinv[s] * dinv[d];
    int pos = atomicAdd(&cursor[d], 1);
    esort[pos] = make_int2(s, __float_as_int(nm));
}

// ---------------------------------------------------------------------------
// conv: wave per row. 64 lanes = 4 edge-slots (es) x 16 float4 slices (f4).
// Each es-slot accumulates a private float4 in REGISTERS (no atomics);
// cross-slot reduction via __shfl_xor(16,32); lanes 0-15 store one float4.
// float4 gathers = 4x fewer VMEM instructions than scalar conv_csr.
// ---------------------------------------------------------------------------
__global__ __launch_bounds__(256) void conv_reg_kernel(const float4* __restrict__ x4,
                                                       const int* __restrict__ rowptr,
                                                       const int2* __restrict__ esort,
                                                       float4* __restrict__ out4, int n) {
    int row = blockIdx.x * 4 + (threadIdx.x >> 6);
    if (row >= n) return;
    int lane = threadIdx.x & 63;
    int es = lane >> 4, f4 = lane & 15;
    int beg = rowptr[row], end = rowptr[row + 1];
    float4 acc = make_float4(0.f, 0.f, 0.f, 0.f);
    for (int base = beg; base < end; base += 64) {
        int m = end - base;
        if (m > 64) m = 64;
        int2 pk = (lane < m) ? esort[base + lane] : make_int2(0, 0);
        int iters = (m + 3) >> 2;
        int k = 0;
        for (; k + 2 <= iters; k += 2) {
            int i0 = 4 * k + es, i1 = i0 + 4;
            int sx0 = __shfl(pk.x, i0, 64), w0i = __shfl(pk.y, i0, 64);
            int sx1 = __shfl(pk.x, i1, 64), w1i = __shfl(pk.y, i1, 64);
            float w0 = (i0 < m) ? __int_as_float(w0i) : 0.0f;
            float w1 = (i1 < m) ? __int_as_float(w1i) : 0.0f;
            float4 v0 = x4[(size_t)sx0 * 16 + f4];
            float4 v1 = x4[(size_t)sx1 * 16 + f4];
            acc.x = fmaf(v0.x, w0, acc.x); acc.y = fmaf(v0.y, w0, acc.y);
            acc.z = fmaf(v0.z, w0, acc.z); acc.w = fmaf(v0.w, w0, acc.w);
            acc.x = fmaf(v1.x, w1, acc.x); acc.y = fmaf(v1.y, w1, acc.y);
            acc.z = fmaf(v1.z, w1, acc.z); acc.w = fmaf(v1.w, w1, acc.w);
        }
        if (k < iters) {
            int i0 = 4 * k + es;
            int sx0 = __shfl(pk.x, i0, 64), w0i = __shfl(pk.y, i0, 64);
            float w0 = (i0 < m) ? __int_as_float(w0i) : 0.0f;
            float4 v0 = x4[(size_t)sx0 * 16 + f4];
            acc.x = fmaf(v0.x, w0, acc.x); acc.y = fmaf(v0.y, w0, acc.y);
            acc.z = fmaf(v0.z, w0, acc.z); acc.w = fmaf(v0.w, w0, acc.w);
        }
    }
    // reduce the 4 es-slot partials (lanes differing in bits 4,5)
#pragma unroll
    for (int off = 16; off <= 32; off <<= 1) {
        acc.x += __shfl_xor(acc.x, off, 64);
        acc.y += __shfl_xor(acc.y, off, 64);
        acc.z += __shfl_xor(acc.z, off, 64);
        acc.w += __shfl_xor(acc.w, off, 64);
    }
    if (es == 0) out4[(size_t)row * 16 + f4] = acc;
}

// ---------------------------------------------------------------------------
// Register-tiled lin kernels (round-4 proven versions, verbatim).
// ---------------------------------------------------------------------------
__device__ __forceinline__ float4 relu4(float4 v) {
    v.x = fmaxf(v.x, 0.0f); v.y = fmaxf(v.y, 0.0f);
    v.z = fmaxf(v.z, 0.0f); v.w = fmaxf(v.w, 0.0f);
    return v;
}

__global__ __launch_bounds__(256) void lin1_kernel(const float* __restrict__ h,
                                                   const float* __restrict__ W1,
                                                   const float* __restrict__ b1,
                                                   float* __restrict__ out, int n) {
    __shared__ float wt[64 * 64];
    __shared__ float ht[64 * 64];
    int t = threadIdx.x;
    for (int i = t; i < 64 * 64; i += 256) {
        int k = i >> 6, c = i & 63;
        int kq = k >> 2, slot = kq ^ (c & 7);
        wt[c * 64 + slot * 4 + (k & 3)] = W1[i];
    }
    int row0 = blockIdx.x * 64;
    const float4* h4 = (const float4*)h;
    float4* ht4 = (float4*)ht;
#pragma unroll
    for (int j = 0; j < 4; ++j) {
        int flat = t + 256 * j;
        int r = flat >> 4;
        int kq = flat & 15;
        int gr = row0 + r;
        float4 v = (gr < n) ? relu4(h4[(size_t)gr * 16 + kq])
                            : make_float4(0.f, 0.f, 0.f, 0.f);
        ht4[r * 16 + (kq ^ ((r >> 2) & 7))] = v;
    }
    __syncthreads();
    const float4* wt4 = (const float4*)wt;
    const float4* ht4c = (const float4*)ht;

    int tx = t & 15, ty = t >> 4;
    float acc[4][4] = {};
#pragma unroll 2
    for (int kq = 0; kq < 16; ++kq) {
        int wslot = kq ^ (tx & 7);
        float4 b0 = wt4[(tx +  0) * 16 + wslot];
        float4 b1v = wt4[(tx + 16) * 16 + wslot];
        float4 b2v = wt4[(tx + 32) * 16 + wslot];
        float4 b3v = wt4[(tx + 48) * 16 + wslot];
        int aslot = kq ^ (ty & 7);
#pragma unroll
        for (int i = 0; i < 4; ++i) {
            float4 a = ht4c[(4 * ty + i) * 16 + aslot];
            acc[i][0] = fmaf(a.x, b0.x,  fmaf(a.y, b0.y,  fmaf(a.z, b0.z,  fmaf(a.w, b0.w,  acc[i][0]))));
            acc[i][1] = fmaf(a.x, b1v.x, fmaf(a.y, b1v.y, fmaf(a.z, b1v.z, fmaf(a.w, b1v.w, acc[i][1]))));
            acc[i][2] = fmaf(a.x, b2v.x, fmaf(a.y, b2v.y, fmaf(a.z, b2v.z, fmaf(a.w, b2v.w, acc[i][2]))));
            acc[i][3] = fmaf(a.x, b3v.x, fmaf(a.y, b3v.y, fmaf(a.z, b3v.z, fmaf(a.w, b3v.w, acc[i][3]))));
        }
    }
    float bj[4];
#pragma unroll
    for (int g = 0; g < 4; ++g) bj[g] = b1[tx + 16 * g];
    int r0 = row0 + 4 * ty;
#pragma unroll
    for (int i = 0; i < 4; ++i) {
        int r = r0 + i;
        if (r >= n) break;
#pragma unroll
        for (int g = 0; g < 4; ++g)
            out[(size_t)r * 64 + tx + 16 * g] = fmaxf(acc[i][g] + bj[g], 0.0f);
    }
}

__global__ __launch_bounds__(256) void lin2_kernel(const float* __restrict__ h,
                                                   const float* __restrict__ W2,
                                                   const float* __restrict__ b2,
                                                   float* __restrict__ out, int n) {
    __shared__ float wt[64 * 64];   // cols >= 47 zero-padded
    __shared__ float ht[64 * 64];
    int t = threadIdx.x;
    for (int i = t; i < 64 * 64; i += 256) {
        int k = i >> 6, c = i & 63;
        int kq = k >> 2, slot = kq ^ (c & 7);
        wt[c * 64 + slot * 4 + (k & 3)] = (c < NC) ? W2[k * NC + c] : 0.0f;
    }
    int row0 = blockIdx.x * 64;
    const float4* h4 = (const float4*)h;
    float4* ht4 = (float4*)ht;
#pragma unroll
    for (int j = 0; j < 4; ++j) {
        int flat = t + 256 * j;
        int r = flat >> 4;
        int kq = flat & 15;
        int gr = row0 + r;
        float4 v = (gr < n) ? relu4(h4[(size_t)gr * 16 + kq])
                            : make_float4(0.f, 0.f, 0.f, 0.f);
        ht4[r * 16 + (kq ^ ((r >> 2) & 7))] = v;
    }
    __syncthreads();
    const float4* wt4 = (const float4*)wt;
    const float4* ht4c = (const float4*)ht;

    int tx = t & 15, ty = t >> 4;
    float acc[4][4] = {};
#pragma unroll 2
    for (int kq = 0; kq < 16; ++kq) {
        int wslot = kq ^ (tx & 7);
        float4 b0 = wt4[(tx +  0) * 16 + wslot];
        float4 b1v = wt4[(tx + 16) * 16 + wslot];
        float4 b2v = wt4[(tx + 32) * 16 + wslot];
        float4 b3v = wt4[(tx + 48) * 16 + wslot];
        int aslot = kq ^ (ty & 7);
#pragma unroll
        for (int i = 0; i < 4; ++i) {
            float4 a = ht4c[(4 * ty + i) * 16 + aslot];
            acc[i][0] = fmaf(a.x, b0.x,  fmaf(a.y, b0.y,  fmaf(a.z, b0.z,  fmaf(a.w, b0.w,  acc[i][0]))));
            acc[i][1] = fmaf(a.x, b1v.x, fmaf(a.y, b1v.y, fmaf(a.z, b1v.z, fmaf(a.w, b1v.w, acc[i][1]))));
            acc[i][2] = fmaf(a.x, b2v.x, fmaf(a.y, b2v.y, fmaf(a.z, b2v.z, fmaf(a.w, b2v.w, acc[i][2]))));
            acc[i][3] = fmaf(a.x, b3v.x, fmaf(a.y, b3v.y, fmaf(a.z, b3v.z, fmaf(a.w, b3v.w, acc[i][3]))));
        }
    }
    bool vm[4];
    float bj[4];
#pragma unroll
    for (int g = 0; g < 4; ++g) {
        int c = tx + 16 * g;
        vm[g] = (c < NC);
        bj[g] = vm[g] ? b2[c] : 0.0f;
    }
    int r0 = row0 + 4 * ty;
#pragma unroll
    for (int i = 0; i < 4; ++i) {
        int r = r0 + i;
        float v[4];
        float m = -INFINITY;
#pragma unroll
        for (int g = 0; g < 4; ++g) {
            v[g] = acc[i][g] + bj[g];
            if (vm[g]) m = fmaxf(m, v[g]);
        }
#pragma unroll
        for (int off = 8; off > 0; off >>= 1) m = fmaxf(m, __shfl_xor(m, off, 64));
        float s = 0.0f;
#pragma unroll
        for (int g = 0; g < 4; ++g)
            if (vm[g]) s += expf(v[g] - m);
#pragma unroll
        for (int off = 8; off > 0; off >>= 1) s += __shfl_xor(s, off, 64);
        float lse = m + logf(s);
        if (r < n) {
#pragma unroll
            for (int g = 0; g < 4; ++g)
                if (vm[g]) out[(size_t)r * NC + tx + 16 * g] = v[g] - lse;
        }
    }
}

// ---------------------------------------------------------------------------
extern "C" void kernel_launch(void* const* d_in, const int* in_sizes, int n_in,
                              void* d_out, int out_size, void* d_ws, size_t ws_size,
                              hipStream_t stream) {
    const float* x  = (const float*)d_in[0];
    const void*  ei = d_in[1];
    const float* W1 = (const float*)d_in[2];
    const float* b1 = (const float*)d_in[3];
    const float* W2 = (const float*)d_in[4];
    const float* b2 = (const float*)d_in[5];
    float* out = (float*)d_out;

    const int E = in_sizes[1] / 2;
    const int n2e = in_sizes[1];
    const int NB = (NN + SCAN_BLK - 1) / SCAN_BLK;   // 98 <= 256

    // workspace carve-out (256B aligned) — round-4 footprint
    char* ws = (char*)d_ws;
    size_t off = 0;
    auto alloc = [&](size_t bytes) -> void* {
        void* p = ws + off;
        off = (off + bytes + 255) & ~(size_t)255;
        return p;
    };
    int*   flag   = (int*)  alloc(4);
    int*   deg    = (int*)  alloc((size_t)NN * 4);
    float* dinv   = (float*)alloc((size_t)NN * 4);
    int*   e32    = (int*)  alloc((size_t)n2e * 4);        // src32 | dst32
    int*   excl   = (int*)  alloc((size_t)NN * 4);
    int*   bsum   = (int*)  alloc(256 * 4);
    int*   rowptr = (int*)  alloc((size_t)(NN + 1) * 4);
    int*   cursor = (int*)  alloc((size_t)NN * 4);
    int2*  esort  = (int2*) alloc((size_t)E * 8);
    float* bufA   = (float*)alloc((size_t)NN * F * 4);
    float* bufB   = (float*)alloc((size_t)NN * F * 4);
    int* src32 = e32;
    int* dst32 = e32 + E;

    hipMemsetAsync(deg, 0, (size_t)NN * 4, stream);

    detect_kernel<<<1, 64, 0, stream>>>(ei, flag);
    convert_kernel<<<(n2e + 255) / 256, 256, 0, stream>>>(ei, flag, e32, n2e);

    deg_kernel <<<(E + 255) / 256, 256, 0, stream>>>(dst32, deg, E);
    dinv_kernel<<<(NN + 255) / 256, 256, 0, stream>>>(deg, dinv, NN);

    scan1_kernel<<<NB, 256, 0, stream>>>(deg, excl, bsum, NN);
    scan2_kernel<<<1, 256, 0, stream>>>(bsum, NB);
    scan3_kernel<<<(NN + 255) / 256, 256, 0, stream>>>(excl, bsum, rowptr, cursor, NN, E);

    scatter_kernel<<<(E + 255) / 256, 256, 0, stream>>>(src32, dst32, dinv, cursor, esort, E);

    const int conv_blocks = (NN + 3) / 4;     // wave per row, 4 waves/block
    const int lin_blocks = (NN + 63) / 64;    // 1563

    // conv1: x -> bufA (raw conv sums)
    conv_reg_kernel<<<conv_blocks, 256, 0, stream>>>(
        (const float4*)x, rowptr, esort, (float4*)bufA, NN);

    // lin1: relu(bufA) @ W1 + b1, relu -> bufB
    lin1_kernel<<<lin_blocks, 256, 0, stream>>>(bufA, W1, b1, bufB, NN);

    // conv2: bufB -> bufA (raw conv sums)
    conv_reg_kernel<<<conv_blocks, 256, 0, stream>>>(
        (const float4*)bufB, rowptr, esort, (float4*)bufA, NN);

    // lin2 + log_softmax
    lin2_kernel<<<lin_blocks, 256, 0, stream>>>(bufA, W2, b2, out, NN);
}

// Round 8
// 310.678 us; speedup vs baseline: 5.0952x; 1.0498x over previous
//
#include <hip/hip_runtime.h>
#include <math.h>

#define NN 100000
#define F 64
#define NC 47
#define NSUP 98        // ceil(NN/1024) super-bins
#define SUPR 1024      // rows per super-bin
#define CHUNK 8192     // edges per binA block

// ---------------------------------------------------------------------------
// Edge dtype handling: harness may deliver edge_index as int32 or int64.
// ---------------------------------------------------------------------------
__global__ void detect_kernel(const void* __restrict__ ei, int* __restrict__ flag) {
    const int* e32 = (const int*)ei;
    int i = threadIdx.x;                 // 64 threads
    int v = e32[2 * i + 1];
    unsigned long long ball = __ballot(v == 0);
    if (i == 0) *flag = (ball == ~0ULL) ? 1 : 0;  // all-zero odd words => int64
}

__global__ void convert_kernel(const void* __restrict__ ei, const int* __restrict__ flag,
                               int* __restrict__ out, int n2e) {
    int i = blockIdx.x * blockDim.x + threadIdx.x;
    if (i >= n2e) return;
    if (*flag)
        out[i] = (int)((const long long*)ei)[i];
    else
        out[i] = ((const int*)ei)[i];
}

// ---------------------------------------------------------------------------
// degree + dinv
// ---------------------------------------------------------------------------
__global__ void deg_kernel(const int* __restrict__ dst, int* __restrict__ deg, int E) {
    int e = blockIdx.x * blockDim.x + threadIdx.x;
    if (e < E) atomicAdd(&deg[dst[e]], 1);
}

__global__ void dinv_kernel(const int* __restrict__ deg, float* __restrict__ dinv, int n) {
    int i = blockIdx.x * blockDim.x + threadIdx.x;
    if (i < n) {
        int d = deg[i];
        dinv[i] = (d > 0) ? rsqrtf((float)d) : 0.0f;
    }
}

// ---------------------------------------------------------------------------
// superCnt[s] = sum of deg over the super-bin's 1024 rows
// ---------------------------------------------------------------------------
__global__ __launch_bounds__(256) void supersum_kernel(const int* __restrict__ deg,
                                                       int* __restrict__ superCnt) {
    __shared__ int red[256];
    int s = blockIdx.x, t = threadIdx.x;
    int base = s * SUPR + t * 4;
    int v = 0;
#pragma unroll
    for (int j = 0; j < 4; ++j) {
        int r = base + j;
        if (r < NN) v += deg[r];
    }
    red[t] = v;
    __syncthreads();
    for (int off = 128; off > 0; off >>= 1) {
        if (t < off) red[t] += red[t + off];
        __syncthreads();
    }
    if (t == 0) superCnt[s] = red[0];
}

// ---------------------------------------------------------------------------
// exclusive scan of superCnt (98) -> superBase[0..98]; init superCur
// ---------------------------------------------------------------------------
__global__ __launch_bounds__(128) void superscan_kernel(const int* __restrict__ superCnt,
                                                        int* __restrict__ superBase,
                                                        int* __restrict__ superCur) {
    __shared__ int sc[128];
    int t = threadIdx.x;
    int v = (t < NSUP) ? superCnt[t] : 0;
    sc[t] = v;
    __syncthreads();
    for (int off = 1; off < 128; off <<= 1) {
        int a = (t >= off) ? sc[t - off] : 0;
        __syncthreads();
        sc[t] += a;
        __syncthreads();
    }
    int excl = sc[t] - v;
    if (t < NSUP) { superBase[t] = excl; superCur[t] = excl; }
    if (t == NSUP - 1) superBase[NSUP] = sc[t];   // == E
}

// ---------------------------------------------------------------------------
// binA: group edges by super-bin via LDS staging -> coalesced runs into
// superArr. Packed payload: src(17b) | dstLocal(10b)<<17.
// ---------------------------------------------------------------------------
__global__ __launch_bounds__(256) void binA_kernel(const int* __restrict__ src,
                                                   const int* __restrict__ dst,
                                                   int* __restrict__ superCur,
                                                   unsigned* __restrict__ superArr, int E) {
    __shared__ unsigned buf[CHUNK];        // 32 KB
    __shared__ unsigned char bo[CHUNK];    // 8 KB
    __shared__ int h[128], st[128], cur[128], gst[128];
    int t = threadIdx.x;
    int cb = blockIdx.x * CHUNK;
    int ce = min(cb + CHUNK, E);
    if (t < 128) h[t] = 0;
    __syncthreads();
    for (int i = cb + t; i < ce; i += 256)
        atomicAdd(&h[dst[i] >> 10], 1);
    __syncthreads();
    int orig = (t < 128) ? h[t] : 0;
    if (t < 128) st[t] = orig;
    __syncthreads();
    for (int off = 1; off < 128; off <<= 1) {
        int a = (t >= off && t < 128) ? st[t - off] : 0;
        __syncthreads();
        if (t < 128) st[t] += a;
        __syncthreads();
    }
    if (t < 128) {
        int excl = st[t] - orig;
        st[t] = excl;
        cur[t] = excl;
        gst[t] = (t < NSUP && orig > 0) ? atomicAdd(&superCur[t], orig) : 0;
    }
    __syncthreads();
    for (int i = cb + t; i < ce; i += 256) {
        int s = src[i], d = dst[i];
        unsigned pk = (unsigned)s | ((unsigned)(d & (SUPR - 1)) << 17);
        int sup = d >> 10;
        int pos = atomicAdd(&cur[sup], 1);
        buf[pos] = pk;
        bo[pos] = (unsigned char)sup;
    }
    __syncthreads();
    int nloc = ce - cb;
    for (int i = t; i < nloc; i += 256) {
        int sup = bo[i];
        superArr[gst[sup] + (i - st[sup])] = buf[i];
    }
}

// ---------------------------------------------------------------------------
// binB: one block per super-bin. LDS histogram of 1024 local rows (int LDS
// atomics), LDS scan -> writes rowptr directly; then rank-and-place edges
// into esort {src, norm}. esort writes are confined to this block's 128 KB
// window (one XCD's L2) -> lines fully covered -> ~1x write amplification.
// norm = dinv[src]*dinv[dst] computed identically to the proven scatter.
// ---------------------------------------------------------------------------
__global__ __launch_bounds__(1024) void binB_kernel(const unsigned* __restrict__ superArr,
                                                    const int* __restrict__ superBase,
                                                    const float* __restrict__ dinv,
                                                    int* __restrict__ rowptr,
                                                    int2* __restrict__ esort, int E) {
    __shared__ int hist[SUPR];
    __shared__ int cur[SUPR];
    __shared__ float dloc[SUPR];
    int s = blockIdx.x, t = threadIdx.x;
    int wb = superBase[s], we = superBase[s + 1];
    int gr = s * SUPR + t;
    hist[t] = 0;
    dloc[t] = (gr < NN) ? dinv[gr] : 0.0f;
    __syncthreads();
    for (int i = wb + t; i < we; i += 1024)
        atomicAdd(&hist[(superArr[i] >> 17) & (SUPR - 1)], 1);
    __syncthreads();
    int myv = hist[t];
    cur[t] = myv;
    __syncthreads();
    for (int off = 1; off < 1024; off <<= 1) {
        int a = (t >= off) ? cur[t - off] : 0;
        __syncthreads();
        cur[t] += a;
        __syncthreads();
    }
    int excl = cur[t] - myv;      // local exclusive offset of row t within super
    if (gr < NN) rowptr[gr] = wb + excl;
    if (s == NSUP - 1 && t == 0) rowptr[NN] = E;
    __syncthreads();
    cur[t] = excl;
    __syncthreads();
    for (int i = wb + t; i < we; i += 1024) {
        unsigned e = superArr[i];
        int r  = (e >> 17) & (SUPR - 1);
        int sx = e & 0x1FFFF;
        int pos = atomicAdd(&cur[r], 1);
        float nm = dinv[sx] * dloc[r];
        esort[wb + pos] = make_int2(sx, __float_as_int(nm));
    }
}

// ---------------------------------------------------------------------------
// conv: wave per row (proven round-7). 64 lanes = 4 edge-slots x 16 float4
// slices; register accumulation, shfl_xor cross-slot reduce, no atomics.
// ---------------------------------------------------------------------------
__global__ __launch_bounds__(256) void conv_reg_kernel(const float4* __restrict__ x4,
                                                       const int* __restrict__ rowptr,
                                                       const int2* __restrict__ esort,
                                                       float4* __restrict__ out4, int n) {
    int row = blockIdx.x * 4 + (threadIdx.x >> 6);
    if (row >= n) return;
    int lane = threadIdx.x & 63;
    int es = lane >> 4, f4 = lane & 15;
    int beg = rowptr[row], end = rowptr[row + 1];
    float4 acc = make_float4(0.f, 0.f, 0.f, 0.f);
    for (int base = beg; base < end; base += 64) {
        int m = end - base;
        if (m > 64) m = 64;
        int2 pk = (lane < m) ? esort[base + lane] : make_int2(0, 0);
        int iters = (m + 3) >> 2;
        int k = 0;
        for (; k + 2 <= iters; k += 2) {
            int i0 = 4 * k + es, i1 = i0 + 4;
            int sx0 = __shfl(pk.x, i0, 64), w0i = __shfl(pk.y, i0, 64);
            int sx1 = __shfl(pk.x, i1, 64), w1i = __shfl(pk.y, i1, 64);
            float w0 = (i0 < m) ? __int_as_float(w0i) : 0.0f;
            float w1 = (i1 < m) ? __int_as_float(w1i) : 0.0f;
            float4 v0 = x4[(size_t)sx0 * 16 + f4];
            float4 v1 = x4[(size_t)sx1 * 16 + f4];
            acc.x = fmaf(v0.x, w0, acc.x); acc.y = fmaf(v0.y, w0, acc.y);
            acc.z = fmaf(v0.z, w0, acc.z); acc.w = fmaf(v0.w, w0, acc.w);
            acc.x = fmaf(v1.x, w1, acc.x); acc.y = fmaf(v1.y, w1, acc.y);
            acc.z = fmaf(v1.z, w1, acc.z); acc.w = fmaf(v1.w, w1, acc.w);
        }
        if (k < iters) {
            int i0 = 4 * k + es;
            int sx0 = __shfl(pk.x, i0, 64), w0i = __shfl(pk.y, i0, 64);
            float w0 = (i0 < m) ? __int_as_float(w0i) : 0.0f;
            float4 v0 = x4[(size_t)sx0 * 16 + f4];
            acc.x = fmaf(v0.x, w0, acc.x); acc.y = fmaf(v0.y, w0, acc.y);
            acc.z = fmaf(v0.z, w0, acc.z); acc.w = fmaf(v0.w, w0, acc.w);
        }
    }
#pragma unroll
    for (int off = 16; off <= 32; off <<= 1) {
        acc.x += __shfl_xor(acc.x, off, 64);
        acc.y += __shfl_xor(acc.y, off, 64);
        acc.z += __shfl_xor(acc.z, off, 64);
        acc.w += __shfl_xor(acc.w, off, 64);
    }
    if (es == 0) out4[(size_t)row * 16 + f4] = acc;
}

// ---------------------------------------------------------------------------
// Register-tiled lin kernels (round-4 proven versions, verbatim).
// ---------------------------------------------------------------------------
__device__ __forceinline__ float4 relu4(float4 v) {
    v.x = fmaxf(v.x, 0.0f); v.y = fmaxf(v.y, 0.0f);
    v.z = fmaxf(v.z, 0.0f); v.w = fmaxf(v.w, 0.0f);
    return v;
}

__global__ __launch_bounds__(256) void lin1_kernel(const float* __restrict__ h,
                                                   const float* __restrict__ W1,
                                                   const float* __restrict__ b1,
                                                   float* __restrict__ out, int n) {
    __shared__ float wt[64 * 64];
    __shared__ float ht[64 * 64];
    int t = threadIdx.x;
    for (int i = t; i < 64 * 64; i += 256) {
        int k = i >> 6, c = i & 63;
        int kq = k >> 2, slot = kq ^ (c & 7);
        wt[c * 64 + slot * 4 + (k & 3)] = W1[i];
    }
    int row0 = blockIdx.x * 64;
    const float4* h4 = (const float4*)h;
    float4* ht4 = (float4*)ht;
#pragma unroll
    for (int j = 0; j < 4; ++j) {
        int flat = t + 256 * j;
        int r = flat >> 4;
        int kq = flat & 15;
        int gr = row0 + r;
        float4 v = (gr < n) ? relu4(h4[(size_t)gr * 16 + kq])
                            : make_float4(0.f, 0.f, 0.f, 0.f);
        ht4[r * 16 + (kq ^ ((r >> 2) & 7))] = v;
    }
    __syncthreads();
    const float4* wt4 = (const float4*)wt;
    const float4* ht4c = (const float4*)ht;

    int tx = t & 15, ty = t >> 4;
    float acc[4][4] = {};
#pragma unroll 2
    for (int kq = 0; kq < 16; ++kq) {
        int wslot = kq ^ (tx & 7);
        float4 b0 = wt4[(tx +  0) * 16 + wslot];
        float4 b1v = wt4[(tx + 16) * 16 + wslot];
        float4 b2v = wt4[(tx + 32) * 16 + wslot];
        float4 b3v = wt4[(tx + 48) * 16 + wslot];
        int aslot = kq ^ (ty & 7);
#pragma unroll
        for (int i = 0; i < 4; ++i) {
            float4 a = ht4c[(4 * ty + i) * 16 + aslot];
            acc[i][0] = fmaf(a.x, b0.x,  fmaf(a.y, b0.y,  fmaf(a.z, b0.z,  fmaf(a.w, b0.w,  acc[i][0]))));
            acc[i][1] = fmaf(a.x, b1v.x, fmaf(a.y, b1v.y, fmaf(a.z, b1v.z, fmaf(a.w, b1v.w, acc[i][1]))));
            acc[i][2] = fmaf(a.x, b2v.x, fmaf(a.y, b2v.y, fmaf(a.z, b2v.z, fmaf(a.w, b2v.w, acc[i][2]))));
            acc[i][3] = fmaf(a.x, b3v.x, fmaf(a.y, b3v.y, fmaf(a.z, b3v.z, fmaf(a.w, b3v.w, acc[i][3]))));
        }
    }
    float bj[4];
#pragma unroll
    for (int g = 0; g < 4; ++g) bj[g] = b1[tx + 16 * g];
    int r0 = row0 + 4 * ty;
#pragma unroll
    for (int i = 0; i < 4; ++i) {
        int r = r0 + i;
        if (r >= n) break;
#pragma unroll
        for (int g = 0; g < 4; ++g)
            out[(size_t)r * 64 + tx + 16 * g] = fmaxf(acc[i][g] + bj[g], 0.0f);
    }
}

__global__ __launch_bounds__(256) void lin2_kernel(const float* __restrict__ h,
                                                   const float* __restrict__ W2,
                                                   const float* __restrict__ b2,
                                                   float* __restrict__ out, int n) {
    __shared__ float wt[64 * 64];   // cols >= 47 zero-padded
    __shared__ float ht[64 * 64];
    int t = threadIdx.x;
    for (int i = t; i < 64 * 64; i += 256) {
        int k = i >> 6, c = i & 63;
        int kq = k >> 2, slot = kq ^ (c & 7);
        wt[c * 64 + slot * 4 + (k & 3)] = (c < NC) ? W2[k * NC + c] : 0.0f;
    }
    int row0 = blockIdx.x * 64;
    const float4* h4 = (const float4*)h;
    float4* ht4 = (float4*)ht;
#pragma unroll
    for (int j = 0; j < 4; ++j) {
        int flat = t + 256 * j;
        int r = flat >> 4;
        int kq = flat & 15;
        int gr = row0 + r;
        float4 v = (gr < n) ? relu4(h4[(size_t)gr * 16 + kq])
                            : make_float4(0.f, 0.f, 0.f, 0.f);
        ht4[r * 16 + (kq ^ ((r >> 2) & 7))] = v;
    }
    __syncthreads();
    const float4* wt4 = (const float4*)wt;
    const float4* ht4c = (const float4*)ht;

    int tx = t & 15, ty = t >> 4;
    float acc[4][4] = {};
#pragma unroll 2
    for (int kq = 0; kq < 16; ++kq) {
        int wslot = kq ^ (tx & 7);
        float4 b0 = wt4[(tx +  0) * 16 + wslot];
        float4 b1v = wt4[(tx + 16) * 16 + wslot];
        float4 b2v = wt4[(tx + 32) * 16 + wslot];
        float4 b3v = wt4[(tx + 48) * 16 + wslot];
        int aslot = kq ^ (ty & 7);
#pragma unroll
        for (int i = 0; i < 4; ++i) {
            float4 a = ht4c[(4 * ty + i) * 16 + aslot];
            acc[i][0] = fmaf(a.x, b0.x,  fmaf(a.y, b0.y,  fmaf(a.z, b0.z,  fmaf(a.w, b0.w,  acc[i][0]))));
            acc[i][1] = fmaf(a.x, b1v.x, fmaf(a.y, b1v.y, fmaf(a.z, b1v.z, fmaf(a.w, b1v.w, acc[i][1]))));
            acc[i][2] = fmaf(a.x, b2v.x, fmaf(a.y, b2v.y, fmaf(a.z, b2v.z, fmaf(a.w, b2v.w, acc[i][2]))));
            acc[i][3] = fmaf(a.x, b3v.x, fmaf(a.y, b3v.y, fmaf(a.z, b3v.z, fmaf(a.w, b3v.w, acc[i][3]))));
        }
    }
    bool vm[4];
    float bj[4];
#pragma unroll
    for (int g = 0; g < 4; ++g) {
        int c = tx + 16 * g;
        vm[g] = (c < NC);
        bj[g] = vm[g] ? b2[c] : 0.0f;
    }
    int r0 = row0 + 4 * ty;
#pragma unroll
    for (int i = 0; i < 4; ++i) {
        int r = r0 + i;
        float v[4];
        float m = -INFINITY;
#pragma unroll
        for (int g = 0; g < 4; ++g) {
            v[g] = acc[i][g] + bj[g];
            if (vm[g]) m = fmaxf(m, v[g]);
        }
#pragma unroll
        for (int off = 8; off > 0; off >>= 1) m = fmaxf(m, __shfl_xor(m, off, 64));
        float s = 0.0f;
#pragma unroll
        for (int g = 0; g < 4; ++g)
            if (vm[g]) s += expf(v[g] - m);
#pragma unroll
        for (int off = 8; off > 0; off >>= 1) s += __shfl_xor(s, off, 64);
        float lse = m + logf(s);
        if (r < n) {
#pragma unroll
            for (int g = 0; g < 4; ++g)
                if (vm[g]) out[(size_t)r * NC + tx + 16 * g] = v[g] - lse;
        }
    }
}

// ---------------------------------------------------------------------------
extern "C" void kernel_launch(void* const* d_in, const int* in_sizes, int n_in,
                              void* d_out, int out_size, void* d_ws, size_t ws_size,
                              hipStream_t stream) {
    const float* x  = (const float*)d_in[0];
    const void*  ei = d_in[1];
    const float* W1 = (const float*)d_in[2];
    const float* b1 = (const float*)d_in[3];
    const float* W2 = (const float*)d_in[4];
    const float* b2 = (const float*)d_in[5];
    float* out = (float*)d_out;

    const int E = in_sizes[1] / 2;
    const int n2e = in_sizes[1];

    // workspace carve-out (256B aligned)
    char* ws = (char*)d_ws;
    size_t off = 0;
    auto alloc = [&](size_t bytes) -> void* {
        void* p = ws + off;
        off = (off + bytes + 255) & ~(size_t)255;
        return p;
    };
    int*      flag      = (int*)     alloc(4);
    int*      deg       = (int*)     alloc((size_t)NN * 4);
    float*    dinv      = (float*)   alloc((size_t)NN * 4);
    int*      e32       = (int*)     alloc((size_t)n2e * 4);       // src32 | dst32
    int*      superCnt  = (int*)     alloc(128 * 4);
    int*      superBase = (int*)     alloc(128 * 4);
    int*      superCur  = (int*)     alloc(128 * 4);
    unsigned* superArr  = (unsigned*)alloc((size_t)E * 4);
    int*      rowptr    = (int*)     alloc((size_t)(NN + 1) * 4);
    int2*     esort     = (int2*)    alloc((size_t)E * 8);
    float*    bufA      = (float*)   alloc((size_t)NN * F * 4);
    float*    bufB      = (float*)   alloc((size_t)NN * F * 4);
    int* src32 = e32;
    int* dst32 = e32 + E;

    hipMemsetAsync(deg, 0, (size_t)NN * 4, stream);

    detect_kernel<<<1, 64, 0, stream>>>(ei, flag);
    convert_kernel<<<(n2e + 255) / 256, 256, 0, stream>>>(ei, flag, e32, n2e);

    deg_kernel <<<(E + 255) / 256, 256, 0, stream>>>(dst32, deg, E);
    dinv_kernel<<<(NN + 255) / 256, 256, 0, stream>>>(deg, dinv, NN);

    supersum_kernel <<<NSUP, 256, 0, stream>>>(deg, superCnt);
    superscan_kernel<<<1, 128, 0, stream>>>(superCnt, superBase, superCur);

    binA_kernel<<<(E + CHUNK - 1) / CHUNK, 256, 0, stream>>>(src32, dst32, superCur, superArr, E);
    binB_kernel<<<NSUP, 1024, 0, stream>>>(superArr, superBase, dinv, rowptr, esort, E);

    const int conv_blocks = (NN + 3) / 4;     // wave per row, 4 waves/block
    const int lin_blocks = (NN + 63) / 64;    // 1563

    // conv1: x -> bufA (raw conv sums)
    conv_reg_kernel<<<conv_blocks, 256, 0, stream>>>(
        (const float4*)x, rowptr, esort, (float4*)bufA, NN);

    // lin1: relu(bufA) @ W1 + b1, relu -> bufB
    lin1_kernel<<<lin_blocks, 256, 0, stream>>>(bufA, W1, b1, bufB, NN);

    // conv2: bufB -> bufA (raw conv sums)
    conv_reg_kernel<<<conv_blocks, 256, 0, stream>>>(
        (const float4*)bufB, rowptr, esort, (float4*)bufA, NN);

    // lin2 + log_softmax
    lin2_kernel<<<lin_blocks, 256, 0, stream>>>(bufA, W2, b2, out, NN);
}

// Round 9
// 249.218 us; speedup vs baseline: 6.3517x; 1.2466x over previous
//
#include <hip/hip_runtime.h>
#include <math.h>

#define NN 100000
#define F 64
#define NC 47
#define NSUP 98        // ceil(NN/1024) super-bins
#define SUPR 1024      // rows per super-bin
#define CHUNK 8192     // edges per binA/supercnt block

// ---------------------------------------------------------------------------
// Edge dtype handling: harness may deliver edge_index as int32 or int64.
// ---------------------------------------------------------------------------
__global__ void detect_kernel(const void* __restrict__ ei, int* __restrict__ flag) {
    const int* e32 = (const int*)ei;
    int i = threadIdx.x;                 // 64 threads
    int v = e32[2 * i + 1];
    unsigned long long ball = __ballot(v == 0);
    if (i == 0) *flag = (ball == ~0ULL) ? 1 : 0;  // all-zero odd words => int64
}

__global__ void convert_kernel(const void* __restrict__ ei, const int* __restrict__ flag,
                               int* __restrict__ out, int n2e) {
    int i = blockIdx.x * blockDim.x + threadIdx.x;
    if (i >= n2e) return;
    if (*flag)
        out[i] = (int)((const long long*)ei)[i];
    else
        out[i] = ((const int*)ei)[i];
}

// ---------------------------------------------------------------------------
// supercnt: LDS-privatized histogram of dst>>10. 98 global atomics per block
// (19k total) instead of 1.6M — kills the 50 MB atomic write-through.
// ---------------------------------------------------------------------------
__global__ __launch_bounds__(256) void supercnt_kernel(const int* __restrict__ dst,
                                                       int* __restrict__ superCnt, int E) {
    __shared__ int h[128];
    int t = threadIdx.x;
    if (t < 128) h[t] = 0;
    __syncthreads();
    int cb = blockIdx.x * CHUNK;
    int ce = min(cb + CHUNK, E);
    for (int i = cb + t; i < ce; i += 256)
        atomicAdd(&h[dst[i] >> 10], 1);
    __syncthreads();
    if (t < NSUP && h[t] > 0) atomicAdd(&superCnt[t], h[t]);
}

// ---------------------------------------------------------------------------
// exclusive scan of superCnt (98) -> superBase[0..98]; init superCur
// ---------------------------------------------------------------------------
__global__ __launch_bounds__(128) void superscan_kernel(const int* __restrict__ superCnt,
                                                        int* __restrict__ superBase,
                                                        int* __restrict__ superCur) {
    __shared__ int sc[128];
    int t = threadIdx.x;
    int v = (t < NSUP) ? superCnt[t] : 0;
    sc[t] = v;
    __syncthreads();
    for (int off = 1; off < 128; off <<= 1) {
        int a = (t >= off) ? sc[t - off] : 0;
        __syncthreads();
        sc[t] += a;
        __syncthreads();
    }
    int excl = sc[t] - v;
    if (t < NSUP) { superBase[t] = excl; superCur[t] = excl; }
    if (t == NSUP - 1) superBase[NSUP] = sc[t];   // == E
}

// ---------------------------------------------------------------------------
// binA: group edges by super-bin via LDS staging -> coalesced runs into
// superArr. Packed payload: src(17b) | dstLocal(10b)<<17.  (round-8 proven)
// ---------------------------------------------------------------------------
__global__ __launch_bounds__(256) void binA_kernel(const int* __restrict__ src,
                                                   const int* __restrict__ dst,
                                                   int* __restrict__ superCur,
                                                   unsigned* __restrict__ superArr, int E) {
    __shared__ unsigned buf[CHUNK];        // 32 KB
    __shared__ unsigned char bo[CHUNK];    // 8 KB
    __shared__ int h[128], st[128], cur[128], gst[128];
    int t = threadIdx.x;
    int cb = blockIdx.x * CHUNK;
    int ce = min(cb + CHUNK, E);
    if (t < 128) h[t] = 0;
    __syncthreads();
    for (int i = cb + t; i < ce; i += 256)
        atomicAdd(&h[dst[i] >> 10], 1);
    __syncthreads();
    int orig = (t < 128) ? h[t] : 0;
    if (t < 128) st[t] = orig;
    __syncthreads();
    for (int off = 1; off < 128; off <<= 1) {
        int a = (t >= off && t < 128) ? st[t - off] : 0;
        __syncthreads();
        if (t < 128) st[t] += a;
        __syncthreads();
    }
    if (t < 128) {
        int excl = st[t] - orig;
        st[t] = excl;
        cur[t] = excl;
        gst[t] = (t < NSUP && orig > 0) ? atomicAdd(&superCur[t], orig) : 0;
    }
    __syncthreads();
    for (int i = cb + t; i < ce; i += 256) {
        int s = src[i], d = dst[i];
        unsigned pk = (unsigned)s | ((unsigned)(d & (SUPR - 1)) << 17);
        int sup = d >> 10;
        int pos = atomicAdd(&cur[sup], 1);
        buf[pos] = pk;
        bo[pos] = (unsigned char)sup;
    }
    __syncthreads();
    int nloc = ce - cb;
    for (int i = t; i < nloc; i += 256) {
        int sup = bo[i];
        superArr[gst[sup] + (i - st[sup])] = buf[i];
    }
}

// ---------------------------------------------------------------------------
// binB1: per super-bin — LDS histogram of the 1024 local rows over the
// super's edge slice (this IS deg, privatized), LDS scan -> rowptr, and
// dinv[gr] = rsqrt(deg) written coalesced. No E-wide global atomics.
// ---------------------------------------------------------------------------
__global__ __launch_bounds__(1024) void binB1_kernel(const unsigned* __restrict__ superArr,
                                                     const int* __restrict__ superBase,
                                                     int* __restrict__ rowptr,
                                                     float* __restrict__ dinv, int E) {
    __shared__ int hist[SUPR];
    __shared__ int sc[SUPR];
    int s = blockIdx.x, t = threadIdx.x;
    int wb = superBase[s], we = superBase[s + 1];
    int gr = s * SUPR + t;
    hist[t] = 0;
    __syncthreads();
    for (int i = wb + t; i < we; i += 1024)
        atomicAdd(&hist[(superArr[i] >> 17) & (SUPR - 1)], 1);
    __syncthreads();
    int myv = hist[t];
    sc[t] = myv;
    __syncthreads();
    for (int off = 1; off < 1024; off <<= 1) {
        int a = (t >= off) ? sc[t - off] : 0;
        __syncthreads();
        sc[t] += a;
        __syncthreads();
    }
    if (gr < NN) {
        rowptr[gr] = wb + sc[t] - myv;                        // local exclusive
        dinv[gr] = (myv > 0) ? rsqrtf((float)myv) : 0.0f;
    }
    if (s == NSUP - 1 && t == 0) rowptr[NN] = E;
}

// ---------------------------------------------------------------------------
// binB2: per super-bin — cursors re-derived from rowptr, rank-and-place into
// esort {src, norm}. Writes confined to the super's contiguous window
// (~1x write amplification, round-8 proven). norm = dinv[src]*dinv[dst]
// byte-identical to the passing round-8 path.
// ---------------------------------------------------------------------------
__global__ __launch_bounds__(1024) void binB2_kernel(const unsigned* __restrict__ superArr,
                                                     const int* __restrict__ superBase,
                                                     const int* __restrict__ rowptr,
                                                     const float* __restrict__ dinv,
                                                     int2* __restrict__ esort) {
    __shared__ int cur[SUPR];
    __shared__ float dloc[SUPR];
    int s = blockIdx.x, t = threadIdx.x;
    int wb = superBase[s], we = superBase[s + 1];
    int gr = s * SUPR + t;
    cur[t] = (gr < NN) ? (rowptr[gr] - wb) : 0;
    dloc[t] = (gr < NN) ? dinv[gr] : 0.0f;
    __syncthreads();
    for (int i = wb + t; i < we; i += 1024) {
        unsigned e = superArr[i];
        int r  = (e >> 17) & (SUPR - 1);
        int sx = e & 0x1FFFF;
        int pos = atomicAdd(&cur[r], 1);
        float nm = dinv[sx] * dloc[r];
        esort[wb + pos] = make_int2(sx, __float_as_int(nm));
    }
}

// ---------------------------------------------------------------------------
// conv: wave per row (proven round-7). 64 lanes = 4 edge-slots x 16 float4
// slices; register accumulation, shfl_xor cross-slot reduce, no atomics.
// ---------------------------------------------------------------------------
__global__ __launch_bounds__(256) void conv_reg_kernel(const float4* __restrict__ x4,
                                                       const int* __restrict__ rowptr,
                                                       const int2* __restrict__ esort,
                                                       float4* __restrict__ out4, int n) {
    int row = blockIdx.x * 4 + (threadIdx.x >> 6);
    if (row >= n) return;
    int lane = threadIdx.x & 63;
    int es = lane >> 4, f4 = lane & 15;
    int beg = rowptr[row], end = rowptr[row + 1];
    float4 acc = make_float4(0.f, 0.f, 0.f, 0.f);
    for (int base = beg; base < end; base += 64) {
        int m = end - base;
        if (m > 64) m = 64;
        int2 pk = (lane < m) ? esort[base + lane] : make_int2(0, 0);
        int iters = (m + 3) >> 2;
        int k = 0;
        for (; k + 2 <= iters; k += 2) {
            int i0 = 4 * k + es, i1 = i0 + 4;
            int sx0 = __shfl(pk.x, i0, 64), w0i = __shfl(pk.y, i0, 64);
            int sx1 = __shfl(pk.x, i1, 64), w1i = __shfl(pk.y, i1, 64);
            float w0 = (i0 < m) ? __int_as_float(w0i) : 0.0f;
            float w1 = (i1 < m) ? __int_as_float(w1i) : 0.0f;
            float4 v0 = x4[(size_t)sx0 * 16 + f4];
            float4 v1 = x4[(size_t)sx1 * 16 + f4];
            acc.x = fmaf(v0.x, w0, acc.x); acc.y = fmaf(v0.y, w0, acc.y);
            acc.z = fmaf(v0.z, w0, acc.z); acc.w = fmaf(v0.w, w0, acc.w);
            acc.x = fmaf(v1.x, w1, acc.x); acc.y = fmaf(v1.y, w1, acc.y);
            acc.z = fmaf(v1.z, w1, acc.z); acc.w = fmaf(v1.w, w1, acc.w);
        }
        if (k < iters) {
            int i0 = 4 * k + es;
            int sx0 = __shfl(pk.x, i0, 64), w0i = __shfl(pk.y, i0, 64);
            float w0 = (i0 < m) ? __int_as_float(w0i) : 0.0f;
            float4 v0 = x4[(size_t)sx0 * 16 + f4];
            acc.x = fmaf(v0.x, w0, acc.x); acc.y = fmaf(v0.y, w0, acc.y);
            acc.z = fmaf(v0.z, w0, acc.z); acc.w = fmaf(v0.w, w0, acc.w);
        }
    }
#pragma unroll
    for (int off = 16; off <= 32; off <<= 1) {
        acc.x += __shfl_xor(acc.x, off, 64);
        acc.y += __shfl_xor(acc.y, off, 64);
        acc.z += __shfl_xor(acc.z, off, 64);
        acc.w += __shfl_xor(acc.w, off, 64);
    }
    if (es == 0) out4[(size_t)row * 16 + f4] = acc;
}

// ---------------------------------------------------------------------------
// Register-tiled lin kernels (round-4 proven versions, verbatim).
// ---------------------------------------------------------------------------
__device__ __forceinline__ float4 relu4(float4 v) {
    v.x = fmaxf(v.x, 0.0f); v.y = fmaxf(v.y, 0.0f);
    v.z = fmaxf(v.z, 0.0f); v.w = fmaxf(v.w, 0.0f);
    return v;
}

__global__ __launch_bounds__(256) void lin1_kernel(const float* __restrict__ h,
                                                   const float* __restrict__ W1,
                                                   const float* __restrict__ b1,
                                                   float* __restrict__ out, int n) {
    __shared__ float wt[64 * 64];
    __shared__ float ht[64 * 64];
    int t = threadIdx.x;
    for (int i = t; i < 64 * 64; i += 256) {
        int k = i >> 6, c = i & 63;
        int kq = k >> 2, slot = kq ^ (c & 7);
        wt[c * 64 + slot * 4 + (k & 3)] = W1[i];
    }
    int row0 = blockIdx.x * 64;
    const float4* h4 = (const float4*)h;
    float4* ht4 = (float4*)ht;
#pragma unroll
    for (int j = 0; j < 4; ++j) {
        int flat = t + 256 * j;
        int r = flat >> 4;
        int kq = flat & 15;
        int gr = row0 + r;
        float4 v = (gr < n) ? relu4(h4[(size_t)gr * 16 + kq])
                            : make_float4(0.f, 0.f, 0.f, 0.f);
        ht4[r * 16 + (kq ^ ((r >> 2) & 7))] = v;
    }
    __syncthreads();
    const float4* wt4 = (const float4*)wt;
    const float4* ht4c = (const float4*)ht;

    int tx = t & 15, ty = t >> 4;
    float acc[4][4] = {};
#pragma unroll 2
    for (int kq = 0; kq < 16; ++kq) {
        int wslot = kq ^ (tx & 7);
        float4 b0 = wt4[(tx +  0) * 16 + wslot];
        float4 b1v = wt4[(tx + 16) * 16 + wslot];
        float4 b2v = wt4[(tx + 32) * 16 + wslot];
        float4 b3v = wt4[(tx + 48) * 16 + wslot];
        int aslot = kq ^ (ty & 7);
#pragma unroll
        for (int i = 0; i < 4; ++i) {
            float4 a = ht4c[(4 * ty + i) * 16 + aslot];
            acc[i][0] = fmaf(a.x, b0.x,  fmaf(a.y, b0.y,  fmaf(a.z, b0.z,  fmaf(a.w, b0.w,  acc[i][0]))));
            acc[i][1] = fmaf(a.x, b1v.x, fmaf(a.y, b1v.y, fmaf(a.z, b1v.z, fmaf(a.w, b1v.w, acc[i][1]))));
            acc[i][2] = fmaf(a.x, b2v.x, fmaf(a.y, b2v.y, fmaf(a.z, b2v.z, fmaf(a.w, b2v.w, acc[i][2]))));
            acc[i][3] = fmaf(a.x, b3v.x, fmaf(a.y, b3v.y, fmaf(a.z, b3v.z, fmaf(a.w, b3v.w, acc[i][3]))));
        }
    }
    float bj[4];
#pragma unroll
    for (int g = 0; g < 4; ++g) bj[g] = b1[tx + 16 * g];
    int r0 = row0 + 4 * ty;
#pragma unroll
    for (int i = 0; i < 4; ++i) {
        int r = r0 + i;
        if (r >= n) break;
#pragma unroll
        for (int g = 0; g < 4; ++g)
            out[(size_t)r * 64 + tx + 16 * g] = fmaxf(acc[i][g] + bj[g], 0.0f);
    }
}

__global__ __launch_bounds__(256) void lin2_kernel(const float* __restrict__ h,
                                                   const float* __restrict__ W2,
                                                   const float* __restrict__ b2,
                                                   float* __restrict__ out, int n) {
    __shared__ float wt[64 * 64];   // cols >= 47 zero-padded
    __shared__ float ht[64 * 64];
    int t = threadIdx.x;
    for (int i = t; i < 64 * 64; i += 256) {
        int k = i >> 6, c = i & 63;
        int kq = k >> 2, slot = kq ^ (c & 7);
        wt[c * 64 + slot * 4 + (k & 3)] = (c < NC) ? W2[k * NC + c] : 0.0f;
    }
    int row0 = blockIdx.x * 64;
    const float4* h4 = (const float4*)h;
    float4* ht4 = (float4*)ht;
#pragma unroll
    for (int j = 0; j < 4; ++j) {
        int flat = t + 256 * j;
        int r = flat >> 4;
        int kq = flat & 15;
        int gr = row0 + r;
        float4 v = (gr < n) ? relu4(h4[(size_t)gr * 16 + kq])
                            : make_float4(0.f, 0.f, 0.f, 0.f);
        ht4[r * 16 + (kq ^ ((r >> 2) & 7))] = v;
    }
    __syncthreads();
    const float4* wt4 = (const float4*)wt;
    const float4* ht4c = (const float4*)ht;

    int tx = t & 15, ty = t >> 4;
    float acc[4][4] = {};
#pragma unroll 2
    for (int kq = 0; kq < 16; ++kq) {
        int wslot = kq ^ (tx & 7);
        float4 b0 = wt4[(tx +  0) * 16 + wslot];
        float4 b1v = wt4[(tx + 16) * 16 + wslot];
        float4 b2v = wt4[(tx + 32) * 16 + wslot];
        float4 b3v = wt4[(tx + 48) * 16 + wslot];
        int aslot = kq ^ (ty & 7);
#pragma unroll
        for (int i = 0; i < 4; ++i) {
            float4 a = ht4c[(4 * ty + i) * 16 + aslot];
            acc[i][0] = fmaf(a.x, b0.x,  fmaf(a.y, b0.y,  fmaf(a.z, b0.z,  fmaf(a.w, b0.w,  acc[i][0]))));
            acc[i][1] = fmaf(a.x, b1v.x, fmaf(a.y, b1v.y, fmaf(a.z, b1v.z, fmaf(a.w, b1v.w, acc[i][1]))));
            acc[i][2] = fmaf(a.x, b2v.x, fmaf(a.y, b2v.y, fmaf(a.z, b2v.z, fmaf(a.w, b2v.w, acc[i][2]))));
            acc[i][3] = fmaf(a.x, b3v.x, fmaf(a.y, b3v.y, fmaf(a.z, b3v.z, fmaf(a.w, b3v.w, acc[i][3]))));
        }
    }
    bool vm[4];
    float bj[4];
#pragma unroll
    for (int g = 0; g < 4; ++g) {
        int c = tx + 16 * g;
        vm[g] = (c < NC);
        bj[g] = vm[g] ? b2[c] : 0.0f;
    }
    int r0 = row0 + 4 * ty;
#pragma unroll
    for (int i = 0; i < 4; ++i) {
        int r = r0 + i;
        float v[4];
        float m = -INFINITY;
#pragma unroll
        for (int g = 0; g < 4; ++g) {
            v[g] = acc[i][g] + bj[g];
            if (vm[g]) m = fmaxf(m, v[g]);
        }
#pragma unroll
        for (int off = 8; off > 0; off >>= 1) m = fmaxf(m, __shfl_xor(m, off, 64));
        float s = 0.0f;
#pragma unroll
        for (int g = 0; g < 4; ++g)
            if (vm[g]) s += expf(v[g] - m);
#pragma unroll
        for (int off = 8; off > 0; off >>= 1) s += __shfl_xor(s, off, 64);
        float lse = m + logf(s);
        if (r < n) {
#pragma unroll
            for (int g = 0; g < 4; ++g)
                if (vm[g]) out[(size_t)r * NC + tx + 16 * g] = v[g] - lse;
        }
    }
}

// ---------------------------------------------------------------------------
extern "C" void kernel_launch(void* const* d_in, const int* in_sizes, int n_in,
                              void* d_out, int out_size, void* d_ws, size_t ws_size,
                              hipStream_t stream) {
    const float* x  = (const float*)d_in[0];
    const void*  ei = d_in[1];
    const float* W1 = (const float*)d_in[2];
    const float* b1 = (const float*)d_in[3];
    const float* W2 = (const float*)d_in[4];
    const float* b2 = (const float*)d_in[5];
    float* out = (float*)d_out;

    const int E = in_sizes[1] / 2;
    const int n2e = in_sizes[1];

    // workspace carve-out (256B aligned)
    char* ws = (char*)d_ws;
    size_t off = 0;
    auto alloc = [&](size_t bytes) -> void* {
        void* p = ws + off;
        off = (off + bytes + 255) & ~(size_t)255;
        return p;
    };
    int*      flag      = (int*)     alloc(4);
    float*    dinv      = (float*)   alloc((size_t)NN * 4);
    int*      e32       = (int*)     alloc((size_t)n2e * 4);       // src32 | dst32
    int*      superCnt  = (int*)     alloc(128 * 4);
    int*      superBase = (int*)     alloc(128 * 4);
    int*      superCur  = (int*)     alloc(128 * 4);
    unsigned* superArr  = (unsigned*)alloc((size_t)E * 4);
    int*      rowptr    = (int*)     alloc((size_t)(NN + 1) * 4);
    int2*     esort     = (int2*)    alloc((size_t)E * 8);
    float*    bufA      = (float*)   alloc((size_t)NN * F * 4);
    float*    bufB      = (float*)   alloc((size_t)NN * F * 4);
    int* src32 = e32;
    int* dst32 = e32 + E;

    hipMemsetAsync(superCnt, 0, 128 * 4, stream);

    detect_kernel<<<1, 64, 0, stream>>>(ei, flag);
    convert_kernel<<<(n2e + 255) / 256, 256, 0, stream>>>(ei, flag, e32, n2e);

    const int chunk_blocks = (E + CHUNK - 1) / CHUNK;   // 196

    supercnt_kernel <<<chunk_blocks, 256, 0, stream>>>(dst32, superCnt, E);
    superscan_kernel<<<1, 128, 0, stream>>>(superCnt, superBase, superCur);

    binA_kernel <<<chunk_blocks, 256, 0, stream>>>(src32, dst32, superCur, superArr, E);
    binB1_kernel<<<NSUP, 1024, 0, stream>>>(superArr, superBase, rowptr, dinv, E);
    binB2_kernel<<<NSUP, 1024, 0, stream>>>(superArr, superBase, rowptr, dinv, esort);

    const int conv_blocks = (NN + 3) / 4;     // wave per row, 4 waves/block
    const int lin_blocks = (NN + 63) / 64;    // 1563

    // conv1: x -> bufA (raw conv sums)
    conv_reg_kernel<<<conv_blocks, 256, 0, stream>>>(
        (const float4*)x, rowptr, esort, (float4*)bufA, NN);

    // lin1: relu(bufA) @ W1 + b1, relu -> bufB
    lin1_kernel<<<lin_blocks, 256, 0, stream>>>(bufA, W1, b1, bufB, NN);

    // conv2: bufB -> bufA (raw conv sums)
    conv_reg_kernel<<<conv_blocks, 256, 0, stream>>>(
        (const float4*)bufB, rowptr, esort, (float4*)bufA, NN);

    // lin2 + log_softmax
    lin2_kernel<<<lin_blocks, 256, 0, stream>>>(bufA, W2, b2, out, NN);
}

// Round 10
// 218.347 us; speedup vs baseline: 7.2497x; 1.1414x over previous
//
#include <hip/hip_runtime.h>
#include <hip/hip_fp16.h>
#include <math.h>

#define NN 100000
#define F 64
#define NC 47
#define NSUP 98        // ceil(NN/1024) super-bins
#define SUPR 1024      // rows per super-bin
#define CHUNK 8192     // edges per prep/binA block

// ---------------------------------------------------------------------------
// Edge dtype handling: harness may deliver edge_index as int32 or int64.
// ---------------------------------------------------------------------------
__global__ void detect_kernel(const void* __restrict__ ei, int* __restrict__ flag) {
    const int* e32 = (const int*)ei;
    int i = threadIdx.x;                 // 64 threads
    int v = e32[2 * i + 1];
    unsigned long long ball = __ballot(v == 0);
    if (i == 0) *flag = (ball == ~0ULL) ? 1 : 0;  // all-zero odd words => int64
}

// ---------------------------------------------------------------------------
// prep: fused convert + super-histogram. Reads ei once (int32 or int64),
// writes clean src32/dst32, LDS-privatized histogram of dst>>10 with 98
// global atomics per block (round-9 supercnt proven structure).
// ---------------------------------------------------------------------------
__global__ __launch_bounds__(256) void prep_kernel(const void* __restrict__ ei,
                                                   const int* __restrict__ flag,
                                                   int* __restrict__ src32,
                                                   int* __restrict__ dst32,
                                                   int* __restrict__ superCnt, int E) {
    __shared__ int h[128];
    int t = threadIdx.x;
    if (t < 128) h[t] = 0;
    __syncthreads();
    int cb = blockIdx.x * CHUNK;
    int ce = min(cb + CHUNK, E);
    bool is64 = (*flag != 0);
    for (int i = cb + t; i < ce; i += 256) {
        int s, d;
        if (is64) {
            s = (int)((const long long*)ei)[i];
            d = (int)((const long long*)ei)[(size_t)E + i];
        } else {
            s = ((const int*)ei)[i];
            d = ((const int*)ei)[(size_t)E + i];
        }
        src32[i] = s;
        dst32[i] = d;
        atomicAdd(&h[d >> 10], 1);
    }
    __syncthreads();
    if (t < NSUP && h[t] > 0) atomicAdd(&superCnt[t], h[t]);
}

// ---------------------------------------------------------------------------
// exclusive scan of superCnt (98) -> superBase[0..98]; init superCur
// ---------------------------------------------------------------------------
__global__ __launch_bounds__(128) void superscan_kernel(const int* __restrict__ superCnt,
                                                        int* __restrict__ superBase,
                                                        int* __restrict__ superCur) {
    __shared__ int sc[128];
    int t = threadIdx.x;
    int v = (t < NSUP) ? superCnt[t] : 0;
    sc[t] = v;
    __syncthreads();
    for (int off = 1; off < 128; off <<= 1) {
        int a = (t >= off) ? sc[t - off] : 0;
        __syncthreads();
        sc[t] += a;
        __syncthreads();
    }
    int excl = sc[t] - v;
    if (t < NSUP) { superBase[t] = excl; superCur[t] = excl; }
    if (t == NSUP - 1) superBase[NSUP] = sc[t];   // == E
}

// ---------------------------------------------------------------------------
// binA: group edges by super-bin via LDS staging -> coalesced runs into
// superArr. Packed payload: src(17b) | dstLocal(10b)<<17.  (round-8 proven)
// ---------------------------------------------------------------------------
__global__ __launch_bounds__(256) void binA_kernel(const int* __restrict__ src,
                                                   const int* __restrict__ dst,
                                                   int* __restrict__ superCur,
                                                   unsigned* __restrict__ superArr, int E) {
    __shared__ unsigned buf[CHUNK];        // 32 KB
    __shared__ unsigned char bo[CHUNK];    // 8 KB
    __shared__ int h[128], st[128], cur[128], gst[128];
    int t = threadIdx.x;
    int cb = blockIdx.x * CHUNK;
    int ce = min(cb + CHUNK, E);
    if (t < 128) h[t] = 0;
    __syncthreads();
    for (int i = cb + t; i < ce; i += 256)
        atomicAdd(&h[dst[i] >> 10], 1);
    __syncthreads();
    int orig = (t < 128) ? h[t] : 0;
    if (t < 128) st[t] = orig;
    __syncthreads();
    for (int off = 1; off < 128; off <<= 1) {
        int a = (t >= off && t < 128) ? st[t - off] : 0;
        __syncthreads();
        if (t < 128) st[t] += a;
        __syncthreads();
    }
    if (t < 128) {
        int excl = st[t] - orig;
        st[t] = excl;
        cur[t] = excl;
        gst[t] = (t < NSUP && orig > 0) ? atomicAdd(&superCur[t], orig) : 0;
    }
    __syncthreads();
    for (int i = cb + t; i < ce; i += 256) {
        int s = src[i], d = dst[i];
        unsigned pk = (unsigned)s | ((unsigned)(d & (SUPR - 1)) << 17);
        int sup = d >> 10;
        int pos = atomicAdd(&cur[sup], 1);
        buf[pos] = pk;
        bo[pos] = (unsigned char)sup;
    }
    __syncthreads();
    int nloc = ce - cb;
    for (int i = t; i < nloc; i += 256) {
        int sup = bo[i];
        superArr[gst[sup] + (i - st[sup])] = buf[i];
    }
}

// ---------------------------------------------------------------------------
// binB1: per super-bin — LDS histogram of the 1024 local rows (= deg,
// privatized), LDS scan -> rowptr, dinv written coalesced. (round-9 proven)
// ---------------------------------------------------------------------------
__global__ __launch_bounds__(1024) void binB1_kernel(const unsigned* __restrict__ superArr,
                                                     const int* __restrict__ superBase,
                                                     int* __restrict__ rowptr,
                                                     float* __restrict__ dinv, int E) {
    __shared__ int hist[SUPR];
    __shared__ int sc[SUPR];
    int s = blockIdx.x, t = threadIdx.x;
    int wb = superBase[s], we = superBase[s + 1];
    int gr = s * SUPR + t;
    hist[t] = 0;
    __syncthreads();
    for (int i = wb + t; i < we; i += 1024)
        atomicAdd(&hist[(superArr[i] >> 17) & (SUPR - 1)], 1);
    __syncthreads();
    int myv = hist[t];
    sc[t] = myv;
    __syncthreads();
    for (int off = 1; off < 1024; off <<= 1) {
        int a = (t >= off) ? sc[t - off] : 0;
        __syncthreads();
        sc[t] += a;
        __syncthreads();
    }
    if (gr < NN) {
        rowptr[gr] = wb + sc[t] - myv;                        // local exclusive
        dinv[gr] = (myv > 0) ? rsqrtf((float)myv) : 0.0f;
    }
    if (s == NSUP - 1 && t == 0) rowptr[NN] = E;
}

// ---------------------------------------------------------------------------
// binB2: per super-bin — rank-and-place into esort {src, norm}. Writes
// confined to the super's window (~1x amplification). (round-9 proven)
// ---------------------------------------------------------------------------
__global__ __launch_bounds__(1024) void binB2_kernel(const unsigned* __restrict__ superArr,
                                                     const int* __restrict__ superBase,
                                                     const int* __restrict__ rowptr,
                                                     const float* __restrict__ dinv,
                                                     int2* __restrict__ esort) {
    __shared__ int cur[SUPR];
    __shared__ float dloc[SUPR];
    int s = blockIdx.x, t = threadIdx.x;
    int wb = superBase[s], we = superBase[s + 1];
    int gr = s * SUPR + t;
    cur[t] = (gr < NN) ? (rowptr[gr] - wb) : 0;
    dloc[t] = (gr < NN) ? dinv[gr] : 0.0f;
    __syncthreads();
    for (int i = wb + t; i < we; i += 1024) {
        unsigned e = superArr[i];
        int r  = (e >> 17) & (SUPR - 1);
        int sx = e & 0x1FFFF;
        int pos = atomicAdd(&cur[r], 1);
        float nm = dinv[sx] * dloc[r];
        esort[wb + pos] = make_int2(sx, __float_as_int(nm));
    }
}

// ---------------------------------------------------------------------------
// f2h: convert a row-major f32 feature matrix to fp16 (4 elems/thread)
// ---------------------------------------------------------------------------
__global__ void f2h_kernel(const float4* __restrict__ in4, uint2* __restrict__ outh, int n4) {
    int i = blockIdx.x * blockDim.x + threadIdx.x;
    if (i >= n4) return;
    float4 v = in4[i];
    __half2 h01 = __floats2half2_rn(v.x, v.y);
    __half2 h23 = __floats2half2_rn(v.z, v.w);
    uint2 r;
    r.x = *(const unsigned*)&h01;
    r.y = *(const unsigned*)&h23;
    outh[i] = r;
}

// ---------------------------------------------------------------------------
// conv: wave per row, fp16 gather operand (128 B/row = half the traffic of
// f32), f32 accumulation. 64 lanes = 4 edge-slots x 16 half4-slices (8 B);
// register accumulation, shfl_xor cross-slot reduce, f32 output. No atomics.
// ---------------------------------------------------------------------------
__global__ __launch_bounds__(256) void conv_half_kernel(const uint2* __restrict__ xh,
                                                        const int* __restrict__ rowptr,
                                                        const int2* __restrict__ esort,
                                                        float4* __restrict__ out4, int n) {
    int row = blockIdx.x * 4 + (threadIdx.x >> 6);
    if (row >= n) return;
    int lane = threadIdx.x & 63;
    int es = lane >> 4, f4 = lane & 15;
    int beg = rowptr[row], end = rowptr[row + 1];
    float4 acc = make_float4(0.f, 0.f, 0.f, 0.f);
    for (int base = beg; base < end; base += 64) {
        int m = end - base;
        if (m > 64) m = 64;
        int2 pk = (lane < m) ? esort[base + lane] : make_int2(0, 0);
        int iters = (m + 3) >> 2;
        int k = 0;
        for (; k + 2 <= iters; k += 2) {
            int i0 = 4 * k + es, i1 = i0 + 4;
            int sx0 = __shfl(pk.x, i0, 64), w0i = __shfl(pk.y, i0, 64);
            int sx1 = __shfl(pk.x, i1, 64), w1i = __shfl(pk.y, i1, 64);
            float w0 = (i0 < m) ? __int_as_float(w0i) : 0.0f;
            float w1 = (i1 < m) ? __int_as_float(w1i) : 0.0f;
            uint2 v0 = xh[(size_t)sx0 * 16 + f4];
            uint2 v1 = xh[(size_t)sx1 * 16 + f4];
            float2 a01 = __half22float2(*reinterpret_cast<const __half2*>(&v0.x));
            float2 a23 = __half22float2(*reinterpret_cast<const __half2*>(&v0.y));
            float2 b01 = __half22float2(*reinterpret_cast<const __half2*>(&v1.x));
            float2 b23 = __half22float2(*reinterpret_cast<const __half2*>(&v1.y));
            acc.x = fmaf(a01.x, w0, acc.x); acc.y = fmaf(a01.y, w0, acc.y);
            acc.z = fmaf(a23.x, w0, acc.z); acc.w = fmaf(a23.y, w0, acc.w);
            acc.x = fmaf(b01.x, w1, acc.x); acc.y = fmaf(b01.y, w1, acc.y);
            acc.z = fmaf(b23.x, w1, acc.z); acc.w = fmaf(b23.y, w1, acc.w);
        }
        if (k < iters) {
            int i0 = 4 * k + es;
            int sx0 = __shfl(pk.x, i0, 64), w0i = __shfl(pk.y, i0, 64);
            float w0 = (i0 < m) ? __int_as_float(w0i) : 0.0f;
            uint2 v0 = xh[(size_t)sx0 * 16 + f4];
            float2 a01 = __half22float2(*reinterpret_cast<const __half2*>(&v0.x));
            float2 a23 = __half22float2(*reinterpret_cast<const __half2*>(&v0.y));
            acc.x = fmaf(a01.x, w0, acc.x); acc.y = fmaf(a01.y, w0, acc.y);
            acc.z = fmaf(a23.x, w0, acc.z); acc.w = fmaf(a23.y, w0, acc.w);
        }
    }
#pragma unroll
    for (int off = 16; off <= 32; off <<= 1) {
        acc.x += __shfl_xor(acc.x, off, 64);
        acc.y += __shfl_xor(acc.y, off, 64);
        acc.z += __shfl_xor(acc.z, off, 64);
        acc.w += __shfl_xor(acc.w, off, 64);
    }
    if (es == 0) out4[(size_t)row * 16 + f4] = acc;
}

// ---------------------------------------------------------------------------
// Register-tiled lin kernels (round-4 proven structure).
// lin1 now emits HALF output (the conv2 gather operand).
// ---------------------------------------------------------------------------
__device__ __forceinline__ float4 relu4(float4 v) {
    v.x = fmaxf(v.x, 0.0f); v.y = fmaxf(v.y, 0.0f);
    v.z = fmaxf(v.z, 0.0f); v.w = fmaxf(v.w, 0.0f);
    return v;
}

__global__ __launch_bounds__(256) void lin1_kernel(const float* __restrict__ h,
                                                   const float* __restrict__ W1,
                                                   const float* __restrict__ b1,
                                                   __half* __restrict__ outh, int n) {
    __shared__ float wt[64 * 64];
    __shared__ float ht[64 * 64];
    int t = threadIdx.x;
    for (int i = t; i < 64 * 64; i += 256) {
        int k = i >> 6, c = i & 63;
        int kq = k >> 2, slot = kq ^ (c & 7);
        wt[c * 64 + slot * 4 + (k & 3)] = W1[i];
    }
    int row0 = blockIdx.x * 64;
    const float4* h4 = (const float4*)h;
    float4* ht4 = (float4*)ht;
#pragma unroll
    for (int j = 0; j < 4; ++j) {
        int flat = t + 256 * j;
        int r = flat >> 4;
        int kq = flat & 15;
        int gr = row0 + r;
        float4 v = (gr < n) ? relu4(h4[(size_t)gr * 16 + kq])
                            : make_float4(0.f, 0.f, 0.f, 0.f);
        ht4[r * 16 + (kq ^ ((r >> 2) & 7))] = v;
    }
    __syncthreads();
    const float4* wt4 = (const float4*)wt;
    const float4* ht4c = (const float4*)ht;

    int tx = t & 15, ty = t >> 4;
    float acc[4][4] = {};
#pragma unroll 2
    for (int kq = 0; kq < 16; ++kq) {
        int wslot = kq ^ (tx & 7);
        float4 b0 = wt4[(tx +  0) * 16 + wslot];
        float4 b1v = wt4[(tx + 16) * 16 + wslot];
        float4 b2v = wt4[(tx + 32) * 16 + wslot];
        float4 b3v = wt4[(tx + 48) * 16 + wslot];
        int aslot = kq ^ (ty & 7);
#pragma unroll
        for (int i = 0; i < 4; ++i) {
            float4 a = ht4c[(4 * ty + i) * 16 + aslot];
            acc[i][0] = fmaf(a.x, b0.x,  fmaf(a.y, b0.y,  fmaf(a.z, b0.z,  fmaf(a.w, b0.w,  acc[i][0]))));
            acc[i][1] = fmaf(a.x, b1v.x, fmaf(a.y, b1v.y, fmaf(a.z, b1v.z, fmaf(a.w, b1v.w, acc[i][1]))));
            acc[i][2] = fmaf(a.x, b2v.x, fmaf(a.y, b2v.y, fmaf(a.z, b2v.z, fmaf(a.w, b2v.w, acc[i][2]))));
            acc[i][3] = fmaf(a.x, b3v.x, fmaf(a.y, b3v.y, fmaf(a.z, b3v.z, fmaf(a.w, b3v.w, acc[i][3]))));
        }
    }
    float bj[4];
#pragma unroll
    for (int g = 0; g < 4; ++g) bj[g] = b1[tx + 16 * g];
    int r0 = row0 + 4 * ty;
#pragma unroll
    for (int i = 0; i < 4; ++i) {
        int r = r0 + i;
        if (r >= n) break;
#pragma unroll
        for (int g = 0; g < 4; ++g)
            outh[(size_t)r * 64 + tx + 16 * g] = __float2half(fmaxf(acc[i][g] + bj[g], 0.0f));
    }
}

__global__ __launch_bounds__(256) void lin2_kernel(const float* __restrict__ h,
                                                   const float* __restrict__ W2,
                                                   const float* __restrict__ b2,
                                                   float* __restrict__ out, int n) {
    __shared__ float wt[64 * 64];   // cols >= 47 zero-padded
    __shared__ float ht[64 * 64];
    int t = threadIdx.x;
    for (int i = t; i < 64 * 64; i += 256) {
        int k = i >> 6, c = i & 63;
        int kq = k >> 2, slot = kq ^ (c & 7);
        wt[c * 64 + slot * 4 + (k & 3)] = (c < NC) ? W2[k * NC + c] : 0.0f;
    }
    int row0 = blockIdx.x * 64;
    const float4* h4 = (const float4*)h;
    float4* ht4 = (float4*)ht;
#pragma unroll
    for (int j = 0; j < 4; ++j) {
        int flat = t + 256 * j;
        int r = flat >> 4;
        int kq = flat & 15;
        int gr = row0 + r;
        float4 v = (gr < n) ? relu4(h4[(size_t)gr * 16 + kq])
                            : make_float4(0.f, 0.f, 0.f, 0.f);
        ht4[r * 16 + (kq ^ ((r >> 2) & 7))] = v;
    }
    __syncthreads();
    const float4* wt4 = (const float4*)wt;
    const float4* ht4c = (const float4*)ht;

    int tx = t & 15, ty = t >> 4;
    float acc[4][4] = {};
#pragma unroll 2
    for (int kq = 0; kq < 16; ++kq) {
        int wslot = kq ^ (tx & 7);
        float4 b0 = wt4[(tx +  0) * 16 + wslot];
        float4 b1v = wt4[(tx + 16) * 16 + wslot];
        float4 b2v = wt4[(tx + 32) * 16 + wslot];
        float4 b3v = wt4[(tx + 48) * 16 + wslot];
        int aslot = kq ^ (ty & 7);
#pragma unroll
        for (int i = 0; i < 4; ++i) {
            float4 a = ht4c[(4 * ty + i) * 16 + aslot];
            acc[i][0] = fmaf(a.x, b0.x,  fmaf(a.y, b0.y,  fmaf(a.z, b0.z,  fmaf(a.w, b0.w,  acc[i][0]))));
            acc[i][1] = fmaf(a.x, b1v.x, fmaf(a.y, b1v.y, fmaf(a.z, b1v.z, fmaf(a.w, b1v.w, acc[i][1]))));
            acc[i][2] = fmaf(a.x, b2v.x, fmaf(a.y, b2v.y, fmaf(a.z, b2v.z, fmaf(a.w, b2v.w, acc[i][2]))));
            acc[i][3] = fmaf(a.x, b3v.x, fmaf(a.y, b3v.y, fmaf(a.z, b3v.z, fmaf(a.w, b3v.w, acc[i][3]))));
        }
    }
    bool vm[4];
    float bj[4];
#pragma unroll
    for (int g = 0; g < 4; ++g) {
        int c = tx + 16 * g;
        vm[g] = (c < NC);
        bj[g] = vm[g] ? b2[c] : 0.0f;
    }
    int r0 = row0 + 4 * ty;
#pragma unroll
    for (int i = 0; i < 4; ++i) {
        int r = r0 + i;
        float v[4];
        float m = -INFINITY;
#pragma unroll
        for (int g = 0; g < 4; ++g) {
            v[g] = acc[i][g] + bj[g];
            if (vm[g]) m = fmaxf(m, v[g]);
        }
#pragma unroll
        for (int off = 8; off > 0; off >>= 1) m = fmaxf(m, __shfl_xor(m, off, 64));
        float s = 0.0f;
#pragma unroll
        for (int g = 0; g < 4; ++g)
            if (vm[g]) s += expf(v[g] - m);
#pragma unroll
        for (int off = 8; off > 0; off >>= 1) s += __shfl_xor(s, off, 64);
        float lse = m + logf(s);
        if (r < n) {
#pragma unroll
            for (int g = 0; g < 4; ++g)
                if (vm[g]) out[(size_t)r * NC + tx + 16 * g] = v[g] - lse;
        }
    }
}

// ---------------------------------------------------------------------------
extern "C" void kernel_launch(void* const* d_in, const int* in_sizes, int n_in,
                              void* d_out, int out_size, void* d_ws, size_t ws_size,
                              hipStream_t stream) {
    const float* x  = (const float*)d_in[0];
    const void*  ei = d_in[1];
    const float* W1 = (const float*)d_in[2];
    const float* b1 = (const float*)d_in[3];
    const float* W2 = (const float*)d_in[4];
    const float* b2 = (const float*)d_in[5];
    float* out = (float*)d_out;

    const int E = in_sizes[1] / 2;

    // workspace carve-out (256B aligned)
    char* ws = (char*)d_ws;
    size_t off = 0;
    auto alloc = [&](size_t bytes) -> void* {
        void* p = ws + off;
        off = (off + bytes + 255) & ~(size_t)255;
        return p;
    };
    int*      flag      = (int*)     alloc(4);
    float*    dinv      = (float*)   alloc((size_t)NN * 4);
    int*      e32       = (int*)     alloc((size_t)E * 2 * 4);     // src32 | dst32
    int*      superCnt  = (int*)     alloc(128 * 4);
    int*      superBase = (int*)     alloc(128 * 4);
    int*      superCur  = (int*)     alloc(128 * 4);
    unsigned* superArr  = (unsigned*)alloc((size_t)E * 4);
    int*      rowptr    = (int*)     alloc((size_t)(NN + 1) * 4);
    int2*     esort     = (int2*)    alloc((size_t)E * 8);
    uint2*    xh        = (uint2*)   alloc((size_t)NN * 16 * 8);   // fp16 x (12.8 MB)
    __half*   bufBh     = (__half*)  alloc((size_t)NN * F * 2);    // fp16 lin1 out
    float*    bufA      = (float*)   alloc((size_t)NN * F * 4);
    int* src32 = e32;
    int* dst32 = e32 + E;

    hipMemsetAsync(superCnt, 0, 128 * 4, stream);

    detect_kernel<<<1, 64, 0, stream>>>(ei, flag);

    const int chunk_blocks = (E + CHUNK - 1) / CHUNK;   // 196

    prep_kernel     <<<chunk_blocks, 256, 0, stream>>>(ei, flag, src32, dst32, superCnt, E);
    superscan_kernel<<<1, 128, 0, stream>>>(superCnt, superBase, superCur);

    binA_kernel <<<chunk_blocks, 256, 0, stream>>>(src32, dst32, superCur, superArr, E);
    binB1_kernel<<<NSUP, 1024, 0, stream>>>(superArr, superBase, rowptr, dinv, E);
    binB2_kernel<<<NSUP, 1024, 0, stream>>>(superArr, superBase, rowptr, dinv, esort);

    // x -> fp16 copy (conv1 gather operand)
    f2h_kernel<<<(NN * 16 + 255) / 256, 256, 0, stream>>>((const float4*)x, xh, NN * 16);

    const int conv_blocks = (NN + 3) / 4;     // wave per row, 4 waves/block
    const int lin_blocks = (NN + 63) / 64;    // 1563

    // conv1: xh -> bufA (raw conv sums, f32)
    conv_half_kernel<<<conv_blocks, 256, 0, stream>>>(xh, rowptr, esort, (float4*)bufA, NN);

    // lin1: relu(bufA) @ W1 + b1, relu -> bufBh (fp16)
    lin1_kernel<<<lin_blocks, 256, 0, stream>>>(bufA, W1, b1, bufBh, NN);

    // conv2: bufBh -> bufA (raw conv sums, f32)
    conv_half_kernel<<<conv_blocks, 256, 0, stream>>>((const uint2*)bufBh, rowptr, esort,
                                                      (float4*)bufA, NN);

    // lin2 + log_softmax
    lin2_kernel<<<lin_blocks, 256, 0, stream>>>(bufA, W2, b2, out, NN);
}

// Round 11
// 188.581 us; speedup vs baseline: 8.3941x; 1.1578x over previous
//
#include <hip/hip_runtime.h>
#include <hip/hip_fp16.h>
#include <math.h>

#define NN 100000
#define F 64
#define NC 47
#define NSUP 98        // ceil(NN/1024) super-bins
#define SUPR 1024      // rows per super-bin
#define ACHUNK 4096    // edges per binA_direct block (LDS int2 stash = 32 KB)
#define PAD 24576      // padded bucket capacity per super (mean 16.3k, sd ~128)

// ---------------------------------------------------------------------------
// Edge dtype handling: harness may deliver edge_index as int32 or int64.
// ---------------------------------------------------------------------------
__global__ void detect_kernel(const void* __restrict__ ei, int* __restrict__ flag) {
    const int* e32 = (const int*)ei;
    int i = threadIdx.x;                 // 64 threads
    int v = e32[2 * i + 1];
    unsigned long long ball = __ballot(v == 0);
    if (i == 0) *flag = (ball == ~0ULL) ? 1 : 0;  // all-zero odd words => int64
}

// ---------------------------------------------------------------------------
// binA_direct: single pass over ei. Per 4096-edge chunk: LDS-stash (s,d),
// LDS histogram by super (dst>>10), reserve a contiguous segment in the
// super's PADDED bucket via one atomicAdd per (block,super), then write
// payload src|dstLocal<<17 directly. The 98 bucket tails are 6 KB of hot
// lines -> L2-resident -> full line coverage, ~1x write amplification
// (unlike round-4's 100k-tail scatter which thrashed per-XCD L2 at 8x).
// ---------------------------------------------------------------------------
__global__ __launch_bounds__(256) void binA_direct_kernel(const void* __restrict__ ei,
                                                          const int* __restrict__ flag,
                                                          int* __restrict__ superCnt,
                                                          unsigned* __restrict__ superArr,
                                                          int E) {
    __shared__ int2 ed[ACHUNK];          // 32 KB
    __shared__ int h[128], gbase[128];
    int t = threadIdx.x;
    if (t < 128) h[t] = 0;
    __syncthreads();
    int cb = blockIdx.x * ACHUNK;
    int ce = min(cb + ACHUNK, E);
    bool is64 = (*flag != 0);
    for (int i = cb + t; i < ce; i += 256) {
        int s, d;
        if (is64) {
            s = (int)((const long long*)ei)[i];
            d = (int)((const long long*)ei)[(size_t)E + i];
        } else {
            s = ((const int*)ei)[i];
            d = ((const int*)ei)[(size_t)E + i];
        }
        ed[i - cb] = make_int2(s, d);
        atomicAdd(&h[d >> 10], 1);
    }
    __syncthreads();
    if (t < 128) {
        int c = h[t];
        gbase[t] = (t < NSUP && c > 0) ? atomicAdd(&superCnt[t], c) : 0;
        h[t] = 0;                         // reuse as local cursor
    }
    __syncthreads();
    int nloc = ce - cb;
    for (int i = t; i < nloc; i += 256) {
        int2 e = ed[i];
        int sup = e.y >> 10;
        int pos = atomicAdd(&h[sup], 1);
        unsigned pk = (unsigned)e.x | ((unsigned)(e.y & (SUPR - 1)) << 17);
        superArr[(size_t)sup * PAD + gbase[sup] + pos] = pk;
    }
}

// ---------------------------------------------------------------------------
// exclusive scan of superCnt (98) -> superBase[0..98]
// ---------------------------------------------------------------------------
__global__ __launch_bounds__(128) void superscan_kernel(const int* __restrict__ superCnt,
                                                        int* __restrict__ superBase) {
    __shared__ int sc[128];
    int t = threadIdx.x;
    int v = (t < NSUP) ? superCnt[t] : 0;
    sc[t] = v;
    __syncthreads();
    for (int off = 1; off < 128; off <<= 1) {
        int a = (t >= off) ? sc[t - off] : 0;
        __syncthreads();
        sc[t] += a;
        __syncthreads();
    }
    if (t < NSUP) superBase[t] = sc[t] - v;
    if (t == NSUP - 1) superBase[NSUP] = sc[t];   // == E
}

// ---------------------------------------------------------------------------
// binB_fused: one block per super. LDS histogram of the 1024 local rows
// (= in-degree, privatized), LDS scan -> rowptr + dinv (coalesced), then
// rank-and-place src indices into compact esrc (4 B payload — norm is
// folded into the prescaled features and the conv writeout).
// ---------------------------------------------------------------------------
__global__ __launch_bounds__(1024) void binB_fused_kernel(const unsigned* __restrict__ superArr,
                                                          const int* __restrict__ superCnt,
                                                          const int* __restrict__ superBase,
                                                          int* __restrict__ rowptr,
                                                          float* __restrict__ dinv,
                                                          unsigned* __restrict__ esrc, int E) {
    __shared__ int hist[SUPR];
    __shared__ int sc[SUPR];
    int s = blockIdx.x, t = threadIdx.x;
    int cnt = superCnt[s];
    int wb = superBase[s];
    const unsigned* arr = superArr + (size_t)s * PAD;
    int gr = s * SUPR + t;
    hist[t] = 0;
    __syncthreads();
    for (int i = t; i < cnt; i += 1024)
        atomicAdd(&hist[(arr[i] >> 17) & (SUPR - 1)], 1);
    __syncthreads();
    int myv = hist[t];
    sc[t] = myv;
    __syncthreads();
    for (int off = 1; off < 1024; off <<= 1) {
        int a = (t >= off) ? sc[t - off] : 0;
        __syncthreads();
        sc[t] += a;
        __syncthreads();
    }
    int excl = sc[t] - myv;
    if (gr < NN) {
        rowptr[gr] = wb + excl;
        dinv[gr] = (myv > 0) ? rsqrtf((float)myv) : 0.0f;
    }
    if (s == NSUP - 1 && t == 0) rowptr[NN] = E;
    __syncthreads();
    hist[t] = excl;                      // reuse as cursor
    __syncthreads();
    for (int i = t; i < cnt; i += 1024) {
        unsigned e = arr[i];
        int r = (e >> 17) & (SUPR - 1);
        int pos = atomicAdd(&hist[r], 1);
        esrc[wb + pos] = e & 0x1FFFFu;
    }
}

// ---------------------------------------------------------------------------
// f2h_scale: xs[r][:] = fp16(x[r][:] * dinv[r])  (prescale by src-side dinv)
// ---------------------------------------------------------------------------
__global__ void f2h_scale_kernel(const float4* __restrict__ in4,
                                 const float* __restrict__ dinv,
                                 uint2* __restrict__ outh, int n4) {
    int i = blockIdx.x * blockDim.x + threadIdx.x;
    if (i >= n4) return;
    float dv = dinv[i >> 4];
    float4 v = in4[i];
    __half2 h01 = __floats2half2_rn(v.x * dv, v.y * dv);
    __half2 h23 = __floats2half2_rn(v.z * dv, v.w * dv);
    uint2 r;
    r.x = *(const unsigned*)&h01;
    r.y = *(const unsigned*)&h23;
    outh[i] = r;
}

// ---------------------------------------------------------------------------
// conv: wave per row, prescaled fp16 gather operand, 4 B edge payload.
// out[row] = dinv[row] * sum_e xs[src_e].  64 lanes = 4 edge-slots x 16
// half4-slices; register accumulation, shfl_xor cross-slot reduce, f32 out.
// ---------------------------------------------------------------------------
__global__ __launch_bounds__(256) void conv_ps_kernel(const uint2* __restrict__ xh,
                                                      const int* __restrict__ rowptr,
                                                      const unsigned* __restrict__ esrc,
                                                      const float* __restrict__ dinv,
                                                      float4* __restrict__ out4, int n) {
    int row = blockIdx.x * 4 + (threadIdx.x >> 6);
    if (row >= n) return;
    int lane = threadIdx.x & 63;
    int es = lane >> 4, f4 = lane & 15;
    int beg = rowptr[row], end = rowptr[row + 1];
    float4 acc = make_float4(0.f, 0.f, 0.f, 0.f);
    for (int base = beg; base < end; base += 64) {
        int m = end - base;
        if (m > 64) m = 64;
        int pk = (lane < m) ? (int)esrc[base + lane] : 0;
        int iters = (m + 3) >> 2;
        int k = 0;
        for (; k + 2 <= iters; k += 2) {
            int i0 = 4 * k + es, i1 = i0 + 4;
            int s0 = __shfl(pk, i0, 64);
            int s1 = __shfl(pk, i1, 64);
            float w0 = (i0 < m) ? 1.0f : 0.0f;
            float w1 = (i1 < m) ? 1.0f : 0.0f;
            uint2 v0 = xh[(size_t)s0 * 16 + f4];
            uint2 v1 = xh[(size_t)s1 * 16 + f4];
            float2 a01 = __half22float2(*reinterpret_cast<const __half2*>(&v0.x));
            float2 a23 = __half22float2(*reinterpret_cast<const __half2*>(&v0.y));
            float2 b01 = __half22float2(*reinterpret_cast<const __half2*>(&v1.x));
            float2 b23 = __half22float2(*reinterpret_cast<const __half2*>(&v1.y));
            acc.x = fmaf(a01.x, w0, acc.x); acc.y = fmaf(a01.y, w0, acc.y);
            acc.z = fmaf(a23.x, w0, acc.z); acc.w = fmaf(a23.y, w0, acc.w);
            acc.x = fmaf(b01.x, w1, acc.x); acc.y = fmaf(b01.y, w1, acc.y);
            acc.z = fmaf(b23.x, w1, acc.z); acc.w = fmaf(b23.y, w1, acc.w);
        }
        if (k < iters) {
            int i0 = 4 * k + es;
            int s0 = __shfl(pk, i0, 64);
            float w0 = (i0 < m) ? 1.0f : 0.0f;
            uint2 v0 = xh[(size_t)s0 * 16 + f4];
            float2 a01 = __half22float2(*reinterpret_cast<const __half2*>(&v0.x));
            float2 a23 = __half22float2(*reinterpret_cast<const __half2*>(&v0.y));
            acc.x = fmaf(a01.x, w0, acc.x); acc.y = fmaf(a01.y, w0, acc.y);
            acc.z = fmaf(a23.x, w0, acc.z); acc.w = fmaf(a23.y, w0, acc.w);
        }
    }
#pragma unroll
    for (int off = 16; off <= 32; off <<= 1) {
        acc.x += __shfl_xor(acc.x, off, 64);
        acc.y += __shfl_xor(acc.y, off, 64);
        acc.z += __shfl_xor(acc.z, off, 64);
        acc.w += __shfl_xor(acc.w, off, 64);
    }
    if (es == 0) {
        float dv = dinv[row];
        acc.x *= dv; acc.y *= dv; acc.z *= dv; acc.w *= dv;
        out4[(size_t)row * 16 + f4] = acc;
    }
}

// ---------------------------------------------------------------------------
// Register-tiled lin kernels (round-4 proven structure).
// lin1 emits fp16(relu(.)*dinv[row]) — the prescaled conv2 operand.
// ---------------------------------------------------------------------------
__device__ __forceinline__ float4 relu4(float4 v) {
    v.x = fmaxf(v.x, 0.0f); v.y = fmaxf(v.y, 0.0f);
    v.z = fmaxf(v.z, 0.0f); v.w = fmaxf(v.w, 0.0f);
    return v;
}

__global__ __launch_bounds__(256) void lin1_kernel(const float* __restrict__ h,
                                                   const float* __restrict__ W1,
                                                   const float* __restrict__ b1,
                                                   const float* __restrict__ dinv,
                                                   __half* __restrict__ outh, int n) {
    __shared__ float wt[64 * 64];
    __shared__ float ht[64 * 64];
    int t = threadIdx.x;
    for (int i = t; i < 64 * 64; i += 256) {
        int k = i >> 6, c = i & 63;
        int kq = k >> 2, slot = kq ^ (c & 7);
        wt[c * 64 + slot * 4 + (k & 3)] = W1[i];
    }
    int row0 = blockIdx.x * 64;
    const float4* h4 = (const float4*)h;
    float4* ht4 = (float4*)ht;
#pragma unroll
    for (int j = 0; j < 4; ++j) {
        int flat = t + 256 * j;
        int r = flat >> 4;
        int kq = flat & 15;
        int gr = row0 + r;
        float4 v = (gr < n) ? relu4(h4[(size_t)gr * 16 + kq])
                            : make_float4(0.f, 0.f, 0.f, 0.f);
        ht4[r * 16 + (kq ^ ((r >> 2) & 7))] = v;
    }
    __syncthreads();
    const float4* wt4 = (const float4*)wt;
    const float4* ht4c = (const float4*)ht;

    int tx = t & 15, ty = t >> 4;
    float acc[4][4] = {};
#pragma unroll 2
    for (int kq = 0; kq < 16; ++kq) {
        int wslot = kq ^ (tx & 7);
        float4 b0 = wt4[(tx +  0) * 16 + wslot];
        float4 b1v = wt4[(tx + 16) * 16 + wslot];
        float4 b2v = wt4[(tx + 32) * 16 + wslot];
        float4 b3v = wt4[(tx + 48) * 16 + wslot];
        int aslot = kq ^ (ty & 7);
#pragma unroll
        for (int i = 0; i < 4; ++i) {
            float4 a = ht4c[(4 * ty + i) * 16 + aslot];
            acc[i][0] = fmaf(a.x, b0.x,  fmaf(a.y, b0.y,  fmaf(a.z, b0.z,  fmaf(a.w, b0.w,  acc[i][0]))));
            acc[i][1] = fmaf(a.x, b1v.x, fmaf(a.y, b1v.y, fmaf(a.z, b1v.z, fmaf(a.w, b1v.w, acc[i][1]))));
            acc[i][2] = fmaf(a.x, b2v.x, fmaf(a.y, b2v.y, fmaf(a.z, b2v.z, fmaf(a.w, b2v.w, acc[i][2]))));
            acc[i][3] = fmaf(a.x, b3v.x, fmaf(a.y, b3v.y, fmaf(a.z, b3v.z, fmaf(a.w, b3v.w, acc[i][3]))));
        }
    }
    float bj[4];
#pragma unroll
    for (int g = 0; g < 4; ++g) bj[g] = b1[tx + 16 * g];
    int r0 = row0 + 4 * ty;
#pragma unroll
    for (int i = 0; i < 4; ++i) {
        int r = r0 + i;
        if (r >= n) break;
        float dv = dinv[r];
#pragma unroll
        for (int g = 0; g < 4; ++g)
            outh[(size_t)r * 64 + tx + 16 * g] =
                __float2half(fmaxf(acc[i][g] + bj[g], 0.0f) * dv);
    }
}

__global__ __launch_bounds__(256) void lin2_kernel(const float* __restrict__ h,
                                                   const float* __restrict__ W2,
                                                   const float* __restrict__ b2,
                                                   float* __restrict__ out, int n) {
    __shared__ float wt[64 * 64];   // cols >= 47 zero-padded
    __shared__ float ht[64 * 64];
    int t = threadIdx.x;
    for (int i = t; i < 64 * 64; i += 256) {
        int k = i >> 6, c = i & 63;
        int kq = k >> 2, slot = kq ^ (c & 7);
        wt[c * 64 + slot * 4 + (k & 3)] = (c < NC) ? W2[k * NC + c] : 0.0f;
    }
    int row0 = blockIdx.x * 64;
    const float4* h4 = (const float4*)h;
    float4* ht4 = (float4*)ht;
#pragma unroll
    for (int j = 0; j < 4; ++j) {
        int flat = t + 256 * j;
        int r = flat >> 4;
        int kq = flat & 15;
        int gr = row0 + r;
        float4 v = (gr < n) ? relu4(h4[(size_t)gr * 16 + kq])
                            : make_float4(0.f, 0.f, 0.f, 0.f);
        ht4[r * 16 + (kq ^ ((r >> 2) & 7))] = v;
    }
    __syncthreads();
    const float4* wt4 = (const float4*)wt;
    const float4* ht4c = (const float4*)ht;

    int tx = t & 15, ty = t >> 4;
    float acc[4][4] = {};
#pragma unroll 2
    for (int kq = 0; kq < 16; ++kq) {
        int wslot = kq ^ (tx & 7);
        float4 b0 = wt4[(tx +  0) * 16 + wslot];
        float4 b1v = wt4[(tx + 16) * 16 + wslot];
        float4 b2v = wt4[(tx + 32) * 16 + wslot];
        float4 b3v = wt4[(tx + 48) * 16 + wslot];
        int aslot = kq ^ (ty & 7);
#pragma unroll
        for (int i = 0; i < 4; ++i) {
            float4 a = ht4c[(4 * ty + i) * 16 + aslot];
            acc[i][0] = fmaf(a.x, b0.x,  fmaf(a.y, b0.y,  fmaf(a.z, b0.z,  fmaf(a.w, b0.w,  acc[i][0]))));
            acc[i][1] = fmaf(a.x, b1v.x, fmaf(a.y, b1v.y, fmaf(a.z, b1v.z, fmaf(a.w, b1v.w, acc[i][1]))));
            acc[i][2] = fmaf(a.x, b2v.x, fmaf(a.y, b2v.y, fmaf(a.z, b2v.z, fmaf(a.w, b2v.w, acc[i][2]))));
            acc[i][3] = fmaf(a.x, b3v.x, fmaf(a.y, b3v.y, fmaf(a.z, b3v.z, fmaf(a.w, b3v.w, acc[i][3]))));
        }
    }
    bool vm[4];
    float bj[4];
#pragma unroll
    for (int g = 0; g < 4; ++g) {
        int c = tx + 16 * g;
        vm[g] = (c < NC);
        bj[g] = vm[g] ? b2[c] : 0.0f;
    }
    int r0 = row0 + 4 * ty;
#pragma unroll
    for (int i = 0; i < 4; ++i) {
        int r = r0 + i;
        float v[4];
        float m = -INFINITY;
#pragma unroll
        for (int g = 0; g < 4; ++g) {
            v[g] = acc[i][g] + bj[g];
            if (vm[g]) m = fmaxf(m, v[g]);
        }
#pragma unroll
        for (int off = 8; off > 0; off >>= 1) m = fmaxf(m, __shfl_xor(m, off, 64));
        float s = 0.0f;
#pragma unroll
        for (int g = 0; g < 4; ++g)
            if (vm[g]) s += expf(v[g] - m);
#pragma unroll
        for (int off = 8; off > 0; off >>= 1) s += __shfl_xor(s, off, 64);
        float lse = m + logf(s);
        if (r < n) {
#pragma unroll
            for (int g = 0; g < 4; ++g)
                if (vm[g]) out[(size_t)r * NC + tx + 16 * g] = v[g] - lse;
        }
    }
}

// ---------------------------------------------------------------------------
extern "C" void kernel_launch(void* const* d_in, const int* in_sizes, int n_in,
                              void* d_out, int out_size, void* d_ws, size_t ws_size,
                              hipStream_t stream) {
    const float* x  = (const float*)d_in[0];
    const void*  ei = d_in[1];
    const float* W1 = (const float*)d_in[2];
    const float* b1 = (const float*)d_in[3];
    const float* W2 = (const float*)d_in[4];
    const float* b2 = (const float*)d_in[5];
    float* out = (float*)d_out;

    const int E = in_sizes[1] / 2;

    // workspace carve-out (256B aligned)
    char* ws = (char*)d_ws;
    size_t off = 0;
    auto alloc = [&](size_t bytes) -> void* {
        void* p = ws + off;
        off = (off + bytes + 255) & ~(size_t)255;
        return p;
    };
    int*      flag      = (int*)     alloc(4);
    float*    dinv      = (float*)   alloc((size_t)NN * 4);
    int*      superCnt  = (int*)     alloc(128 * 4);
    int*      superBase = (int*)     alloc(132 * 4);
    unsigned* superArr  = (unsigned*)alloc((size_t)NSUP * PAD * 4);   // 9.6 MB padded
    int*      rowptr    = (int*)     alloc((size_t)(NN + 1) * 4);
    unsigned* esrc      = (unsigned*)alloc((size_t)E * 4);            // 4 B payload
    uint2*    xh        = (uint2*)   alloc((size_t)NN * 16 * 8);      // fp16 xs
    __half*   bufBh     = (__half*)  alloc((size_t)NN * F * 2);       // fp16 lin1 out
    float*    bufA      = (float*)   alloc((size_t)NN * F * 4);

    hipMemsetAsync(superCnt, 0, 128 * 4, stream);

    detect_kernel<<<1, 64, 0, stream>>>(ei, flag);

    binA_direct_kernel<<<(E + ACHUNK - 1) / ACHUNK, 256, 0, stream>>>(
        ei, flag, superCnt, superArr, E);
    superscan_kernel<<<1, 128, 0, stream>>>(superCnt, superBase);
    binB_fused_kernel<<<NSUP, 1024, 0, stream>>>(
        superArr, superCnt, superBase, rowptr, dinv, esrc, E);

    // xs = fp16(x * dinv[row])  (conv1 gather operand; needs dinv)
    f2h_scale_kernel<<<(NN * 16 + 255) / 256, 256, 0, stream>>>(
        (const float4*)x, dinv, xh, NN * 16);

    const int conv_blocks = (NN + 3) / 4;     // wave per row, 4 waves/block
    const int lin_blocks = (NN + 63) / 64;    // 1563

    // conv1: xs -> bufA (true conv1 output, f32)
    conv_ps_kernel<<<conv_blocks, 256, 0, stream>>>(xh, rowptr, esrc, dinv,
                                                    (float4*)bufA, NN);

    // lin1: relu(bufA) @ W1 + b1, relu, * dinv -> bufBh (fp16, prescaled)
    lin1_kernel<<<lin_blocks, 256, 0, stream>>>(bufA, W1, b1, dinv, bufBh, NN);

    // conv2: bufBh -> bufA (true conv2 output, f32)
    conv_ps_kernel<<<conv_blocks, 256, 0, stream>>>((const uint2*)bufBh, rowptr, esrc,
                                                    dinv, (float4*)bufA, NN);

    // lin2 + log_softmax
    lin2_kernel<<<lin_blocks, 256, 0, stream>>>(bufA, W2, b2, out, NN);
}

// Round 12
// 181.078 us; speedup vs baseline: 8.7419x; 1.0414x over previous
//
#include <hip/hip_runtime.h>
#include <hip/hip_fp16.h>
#include <math.h>

#define NN 100000
#define F 64
#define NC 47
#define NSUP 98        // ceil(NN/1024) super-bins
#define SUPR 1024      // rows per super-bin
#define ACHUNK 4096    // edges per binA_direct block (LDS int2 stash = 32 KB)
#define PAD 24576      // padded bucket capacity per super (mean 16.3k, sd ~127)

// ---------------------------------------------------------------------------
// binA_direct: single pass over ei (dtype detected per-block by wave 0's
// ballot over the first 64 odd words — identical logic to the old detect
// kernel, saves a launch). Per 4096-edge chunk: LDS-stash (s,d), LDS
// histogram by super (dst>>10), reserve a contiguous segment in the super's
// PADDED bucket via one atomicAdd per (block,super), write payload
// src|dstLocal<<17 directly. 98 bucket tails = 6 KB hot lines -> L2-resident
// -> ~1x write amplification. (round-11 proven)
// ---------------------------------------------------------------------------
__global__ __launch_bounds__(256) void binA_direct_kernel(const void* __restrict__ ei,
                                                          int* __restrict__ superCnt,
                                                          unsigned* __restrict__ superArr,
                                                          int E) {
    __shared__ int2 ed[ACHUNK];          // 32 KB
    __shared__ int h[128], gbase[128];
    __shared__ int is64_s;
    int t = threadIdx.x;
    if (t < 64) {
        int v = ((const int*)ei)[2 * t + 1];
        unsigned long long ball = __ballot(v == 0);
        if (t == 0) is64_s = (ball == ~0ULL) ? 1 : 0;   // all-zero odd words => int64
    }
    if (t < 128) h[t] = 0;
    __syncthreads();
    bool is64 = (is64_s != 0);
    int cb = blockIdx.x * ACHUNK;
    int ce = min(cb + ACHUNK, E);
    for (int i = cb + t; i < ce; i += 256) {
        int s, d;
        if (is64) {
            s = (int)((const long long*)ei)[i];
            d = (int)((const long long*)ei)[(size_t)E + i];
        } else {
            s = ((const int*)ei)[i];
            d = ((const int*)ei)[(size_t)E + i];
        }
        ed[i - cb] = make_int2(s, d);
        atomicAdd(&h[d >> 10], 1);
    }
    __syncthreads();
    if (t < 128) {
        int c = h[t];
        gbase[t] = (t < NSUP && c > 0) ? atomicAdd(&superCnt[t], c) : 0;
        h[t] = 0;                         // reuse as local cursor
    }
    __syncthreads();
    int nloc = ce - cb;
    for (int i = t; i < nloc; i += 256) {
        int2 e = ed[i];
        int sup = e.y >> 10;
        int pos = atomicAdd(&h[sup], 1);
        unsigned pk = (unsigned)e.x | ((unsigned)(e.y & (SUPR - 1)) << 17);
        superArr[(size_t)sup * PAD + gbase[sup] + pos] = pk;
    }
}

// ---------------------------------------------------------------------------
// binB_fused: one block per super. Thread 0 serially scans superCnt (98
// entries, L2-hot — replaces the superscan launch); then LDS histogram of
// the 1024 local rows (= in-degree), LDS scan -> rowptr + dinv, then
// rank-and-place src indices into compact esrc. (round-11 proven core)
// ---------------------------------------------------------------------------
__global__ __launch_bounds__(1024) void binB_fused_kernel(const unsigned* __restrict__ superArr,
                                                          const int* __restrict__ superCnt,
                                                          int* __restrict__ rowptr,
                                                          float* __restrict__ dinv,
                                                          unsigned* __restrict__ esrc, int E) {
    __shared__ int hist[SUPR];
    __shared__ int sc[SUPR];
    __shared__ int wb_s;
    int s = blockIdx.x, t = threadIdx.x;
    if (t == 0) {
        int r = 0;
        for (int i = 0; i < s; ++i) r += superCnt[i];
        wb_s = r;
    }
    hist[t] = 0;
    __syncthreads();
    int wb = wb_s;
    int cnt = superCnt[s];
    const unsigned* arr = superArr + (size_t)s * PAD;
    int gr = s * SUPR + t;
    for (int i = t; i < cnt; i += 1024)
        atomicAdd(&hist[(arr[i] >> 17) & (SUPR - 1)], 1);
    __syncthreads();
    int myv = hist[t];
    sc[t] = myv;
    __syncthreads();
    for (int off = 1; off < 1024; off <<= 1) {
        int a = (t >= off) ? sc[t - off] : 0;
        __syncthreads();
        sc[t] += a;
        __syncthreads();
    }
    int excl = sc[t] - myv;
    if (gr < NN) {
        rowptr[gr] = wb + excl;
        dinv[gr] = (myv > 0) ? rsqrtf((float)myv) : 0.0f;
    }
    if (s == NSUP - 1 && t == 0) rowptr[NN] = E;
    __syncthreads();
    hist[t] = excl;                      // reuse as cursor
    __syncthreads();
    for (int i = t; i < cnt; i += 1024) {
        unsigned e = arr[i];
        int r = (e >> 17) & (SUPR - 1);
        int pos = atomicAdd(&hist[r], 1);
        esrc[wb + pos] = e & 0x1FFFFu;
    }
}

// ---------------------------------------------------------------------------
// f2h_scale: xs[r][:] = fp16(x[r][:] * dinv[r])  (prescale by src-side dinv)
// ---------------------------------------------------------------------------
__global__ void f2h_scale_kernel(const float4* __restrict__ in4,
                                 const float* __restrict__ dinv,
                                 uint2* __restrict__ outh, int n4) {
    int i = blockIdx.x * blockDim.x + threadIdx.x;
    if (i >= n4) return;
    float dv = dinv[i >> 4];
    float4 v = in4[i];
    __half2 h01 = __floats2half2_rn(v.x * dv, v.y * dv);
    __half2 h23 = __floats2half2_rn(v.z * dv, v.w * dv);
    uint2 r;
    r.x = *(const unsigned*)&h01;
    r.y = *(const unsigned*)&h23;
    outh[i] = r;
}

// ---------------------------------------------------------------------------
// conv: wave per row, prescaled fp16 gather operand, 4 B edge payload,
// 4-DEEP gather issue: all 4 iterations of a typical row (deg~16 => iters=4)
// have their gathers in flight before any consume — 2x the MLP of round-11.
// out[row] = fp16(dinv[row] * sum_e xs[src_e]).
// ---------------------------------------------------------------------------
__global__ __launch_bounds__(256) void conv_ps_kernel(const uint2* __restrict__ xh,
                                                      const int* __restrict__ rowptr,
                                                      const unsigned* __restrict__ esrc,
                                                      const float* __restrict__ dinv,
                                                      uint2* __restrict__ outh, int n) {
    int row = blockIdx.x * 4 + (threadIdx.x >> 6);
    if (row >= n) return;
    int lane = threadIdx.x & 63;
    int es = lane >> 4, f4 = lane & 15;
    int beg = rowptr[row], end = rowptr[row + 1];
    float4 acc = make_float4(0.f, 0.f, 0.f, 0.f);
    for (int base = beg; base < end; base += 64) {
        int m = end - base;
        if (m > 64) m = 64;
        int pk = (lane < m) ? (int)esrc[base + lane] : 0;
        int iters = (m + 3) >> 2;
        int k = 0;
        for (; k + 4 <= iters; k += 4) {
            int i0 = 4 * k + es, i1 = i0 + 4, i2 = i0 + 8, i3 = i0 + 12;
            int s0 = __shfl(pk, i0, 64);
            int s1 = __shfl(pk, i1, 64);
            int s2 = __shfl(pk, i2, 64);
            int s3 = __shfl(pk, i3, 64);
            float w0 = (i0 < m) ? 1.0f : 0.0f;
            float w1 = (i1 < m) ? 1.0f : 0.0f;
            float w2 = (i2 < m) ? 1.0f : 0.0f;
            float w3 = (i3 < m) ? 1.0f : 0.0f;
            uint2 v0 = xh[(size_t)s0 * 16 + f4];
            uint2 v1 = xh[(size_t)s1 * 16 + f4];
            uint2 v2 = xh[(size_t)s2 * 16 + f4];
            uint2 v3 = xh[(size_t)s3 * 16 + f4];
            float2 a01 = __half22float2(*reinterpret_cast<const __half2*>(&v0.x));
            float2 a23 = __half22float2(*reinterpret_cast<const __half2*>(&v0.y));
            acc.x = fmaf(a01.x, w0, acc.x); acc.y = fmaf(a01.y, w0, acc.y);
            acc.z = fmaf(a23.x, w0, acc.z); acc.w = fmaf(a23.y, w0, acc.w);
            float2 b01 = __half22float2(*reinterpret_cast<const __half2*>(&v1.x));
            float2 b23 = __half22float2(*reinterpret_cast<const __half2*>(&v1.y));
            acc.x = fmaf(b01.x, w1, acc.x); acc.y = fmaf(b01.y, w1, acc.y);
            acc.z = fmaf(b23.x, w1, acc.z); acc.w = fmaf(b23.y, w1, acc.w);
            float2 c01 = __half22float2(*reinterpret_cast<const __half2*>(&v2.x));
            float2 c23 = __half22float2(*reinterpret_cast<const __half2*>(&v2.y));
            acc.x = fmaf(c01.x, w2, acc.x); acc.y = fmaf(c01.y, w2, acc.y);
            acc.z = fmaf(c23.x, w2, acc.z); acc.w = fmaf(c23.y, w2, acc.w);
            float2 d01 = __half22float2(*reinterpret_cast<const __half2*>(&v3.x));
            float2 d23 = __half22float2(*reinterpret_cast<const __half2*>(&v3.y));
            acc.x = fmaf(d01.x, w3, acc.x); acc.y = fmaf(d01.y, w3, acc.y);
            acc.z = fmaf(d23.x, w3, acc.z); acc.w = fmaf(d23.y, w3, acc.w);
        }
        for (; k < iters; ++k) {
            int i0 = 4 * k + es;
            int s0 = __shfl(pk, i0, 64);
            float w0 = (i0 < m) ? 1.0f : 0.0f;
            uint2 v0 = xh[(size_t)s0 * 16 + f4];
            float2 a01 = __half22float2(*reinterpret_cast<const __half2*>(&v0.x));
            float2 a23 = __half22float2(*reinterpret_cast<const __half2*>(&v0.y));
            acc.x = fmaf(a01.x, w0, acc.x); acc.y = fmaf(a01.y, w0, acc.y);
            acc.z = fmaf(a23.x, w0, acc.z); acc.w = fmaf(a23.y, w0, acc.w);
        }
    }
#pragma unroll
    for (int off = 16; off <= 32; off <<= 1) {
        acc.x += __shfl_xor(acc.x, off, 64);
        acc.y += __shfl_xor(acc.y, off, 64);
        acc.z += __shfl_xor(acc.z, off, 64);
        acc.w += __shfl_xor(acc.w, off, 64);
    }
    if (es == 0) {
        float dv = dinv[row];
        __half2 h01 = __floats2half2_rn(acc.x * dv, acc.y * dv);
        __half2 h23 = __floats2half2_rn(acc.z * dv, acc.w * dv);
        uint2 r;
        r.x = *(const unsigned*)&h01;
        r.y = *(const unsigned*)&h23;
        outh[(size_t)row * 16 + f4] = r;
    }
}

// ---------------------------------------------------------------------------
// Register-tiled lin kernels (round-4 proven compute core); h input is now
// fp16 (conv outputs), cvt+relu applied while staging into LDS.
// lin1 emits fp16(relu(.)*dinv[row]) — the prescaled conv2 operand.
// ---------------------------------------------------------------------------
__device__ __forceinline__ float4 h4_to_f4_relu(uint2 hv) {
    float2 a01 = __half22float2(*reinterpret_cast<const __half2*>(&hv.x));
    float2 a23 = __half22float2(*reinterpret_cast<const __half2*>(&hv.y));
    return make_float4(fmaxf(a01.x, 0.f), fmaxf(a01.y, 0.f),
                       fmaxf(a23.x, 0.f), fmaxf(a23.y, 0.f));
}

__global__ __launch_bounds__(256) void lin1_kernel(const uint2* __restrict__ h2,
                                                   const float* __restrict__ W1,
                                                   const float* __restrict__ b1,
                                                   const float* __restrict__ dinv,
                                                   __half* __restrict__ outh, int n) {
    __shared__ float wt[64 * 64];
    __shared__ float ht[64 * 64];
    int t = threadIdx.x;
    for (int i = t; i < 64 * 64; i += 256) {
        int k = i >> 6, c = i & 63;
        int kq = k >> 2, slot = kq ^ (c & 7);
        wt[c * 64 + slot * 4 + (k & 3)] = W1[i];
    }
    int row0 = blockIdx.x * 64;
    float4* ht4 = (float4*)ht;
#pragma unroll
    for (int j = 0; j < 4; ++j) {
        int flat = t + 256 * j;
        int r = flat >> 4;
        int kq = flat & 15;
        int gr = row0 + r;
        float4 v = (gr < n) ? h4_to_f4_relu(h2[(size_t)gr * 16 + kq])
                            : make_float4(0.f, 0.f, 0.f, 0.f);
        ht4[r * 16 + (kq ^ ((r >> 2) & 7))] = v;
    }
    __syncthreads();
    const float4* wt4 = (const float4*)wt;
    const float4* ht4c = (const float4*)ht;

    int tx = t & 15, ty = t >> 4;
    float acc[4][4] = {};
#pragma unroll 2
    for (int kq = 0; kq < 16; ++kq) {
        int wslot = kq ^ (tx & 7);
        float4 b0 = wt4[(tx +  0) * 16 + wslot];
        float4 b1v = wt4[(tx + 16) * 16 + wslot];
        float4 b2v = wt4[(tx + 32) * 16 + wslot];
        float4 b3v = wt4[(tx + 48) * 16 + wslot];
        int aslot = kq ^ (ty & 7);
#pragma unroll
        for (int i = 0; i < 4; ++i) {
            float4 a = ht4c[(4 * ty + i) * 16 + aslot];
            acc[i][0] = fmaf(a.x, b0.x,  fmaf(a.y, b0.y,  fmaf(a.z, b0.z,  fmaf(a.w, b0.w,  acc[i][0]))));
            acc[i][1] = fmaf(a.x, b1v.x, fmaf(a.y, b1v.y, fmaf(a.z, b1v.z, fmaf(a.w, b1v.w, acc[i][1]))));
            acc[i][2] = fmaf(a.x, b2v.x, fmaf(a.y, b2v.y, fmaf(a.z, b2v.z, fmaf(a.w, b2v.w, acc[i][2]))));
            acc[i][3] = fmaf(a.x, b3v.x, fmaf(a.y, b3v.y, fmaf(a.z, b3v.z, fmaf(a.w, b3v.w, acc[i][3]))));
        }
    }
    float bj[4];
#pragma unroll
    for (int g = 0; g < 4; ++g) bj[g] = b1[tx + 16 * g];
    int r0 = row0 + 4 * ty;
#pragma unroll
    for (int i = 0; i < 4; ++i) {
        int r = r0 + i;
        if (r >= n) break;
        float dv = dinv[r];
#pragma unroll
        for (int g = 0; g < 4; ++g)
            outh[(size_t)r * 64 + tx + 16 * g] =
                __float2half(fmaxf(acc[i][g] + bj[g], 0.0f) * dv);
    }
}

__global__ __launch_bounds__(256) void lin2_kernel(const uint2* __restrict__ h2,
                                                   const float* __restrict__ W2,
                                                   const float* __restrict__ b2,
                                                   float* __restrict__ out, int n) {
    __shared__ float wt[64 * 64];   // cols >= 47 zero-padded
    __shared__ float ht[64 * 64];
    int t = threadIdx.x;
    for (int i = t; i < 64 * 64; i += 256) {
        int k = i >> 6, c = i & 63;
        int kq = k >> 2, slot = kq ^ (c & 7);
        wt[c * 64 + slot * 4 + (k & 3)] = (c < NC) ? W2[k * NC + c] : 0.0f;
    }
    int row0 = blockIdx.x * 64;
    float4* ht4 = (float4*)ht;
#pragma unroll
    for (int j = 0; j < 4; ++j) {
        int flat = t + 256 * j;
        int r = flat >> 4;
        int kq = flat & 15;
        int gr = row0 + r;
        float4 v = (gr < n) ? h4_to_f4_relu(h2[(size_t)gr * 16 + kq])
                            : make_float4(0.f, 0.f, 0.f, 0.f);
        ht4[r * 16 + (kq ^ ((r >> 2) & 7))] = v;
    }
    __syncthreads();
    const float4* wt4 = (const float4*)wt;
    const float4* ht4c = (const float4*)ht;

    int tx = t & 15, ty = t >> 4;
    float acc[4][4] = {};
#pragma unroll 2
    for (int kq = 0; kq < 16; ++kq) {
        int wslot = kq ^ (tx & 7);
        float4 b0 = wt4[(tx +  0) * 16 + wslot];
        float4 b1v = wt4[(tx + 16) * 16 + wslot];
        float4 b2v = wt4[(tx + 32) * 16 + wslot];
        float4 b3v = wt4[(tx + 48) * 16 + wslot];
        int aslot = kq ^ (ty & 7);
#pragma unroll
        for (int i = 0; i < 4; ++i) {
            float4 a = ht4c[(4 * ty + i) * 16 + aslot];
            acc[i][0] = fmaf(a.x, b0.x,  fmaf(a.y, b0.y,  fmaf(a.z, b0.z,  fmaf(a.w, b0.w,  acc[i][0]))));
            acc[i][1] = fmaf(a.x, b1v.x, fmaf(a.y, b1v.y, fmaf(a.z, b1v.z, fmaf(a.w, b1v.w, acc[i][1]))));
            acc[i][2] = fmaf(a.x, b2v.x, fmaf(a.y, b2v.y, fmaf(a.z, b2v.z, fmaf(a.w, b2v.w, acc[i][2]))));
            acc[i][3] = fmaf(a.x, b3v.x, fmaf(a.y, b3v.y, fmaf(a.z, b3v.z, fmaf(a.w, b3v.w, acc[i][3]))));
        }
    }
    bool vm[4];
    float bj[4];
#pragma unroll
    for (int g = 0; g < 4; ++g) {
        int c = tx + 16 * g;
        vm[g] = (c < NC);
        bj[g] = vm[g] ? b2[c] : 0.0f;
    }
    int r0 = row0 + 4 * ty;
#pragma unroll
    for (int i = 0; i < 4; ++i) {
        int r = r0 + i;
        float v[4];
        float m = -INFINITY;
#pragma unroll
        for (int g = 0; g < 4; ++g) {
            v[g] = acc[i][g] + bj[g];
            if (vm[g]) m = fmaxf(m, v[g]);
        }
#pragma unroll
        for (int off = 8; off > 0; off >>= 1) m = fmaxf(m, __shfl_xor(m, off, 64));
        float s = 0.0f;
#pragma unroll
        for (int g = 0; g < 4; ++g)
            if (vm[g]) s += expf(v[g] - m);
#pragma unroll
        for (int off = 8; off > 0; off >>= 1) s += __shfl_xor(s, off, 64);
        float lse = m + logf(s);
        if (r < n) {
#pragma unroll
            for (int g = 0; g < 4; ++g)
                if (vm[g]) out[(size_t)r * NC + tx + 16 * g] = v[g] - lse;
        }
    }
}

// ---------------------------------------------------------------------------
extern "C" void kernel_launch(void* const* d_in, const int* in_sizes, int n_in,
                              void* d_out, int out_size, void* d_ws, size_t ws_size,
                              hipStream_t stream) {
    const float* x  = (const float*)d_in[0];
    const void*  ei = d_in[1];
    const float* W1 = (const float*)d_in[2];
    const float* b1 = (const float*)d_in[3];
    const float* W2 = (const float*)d_in[4];
    const float* b2 = (const float*)d_in[5];
    float* out = (float*)d_out;

    const int E = in_sizes[1] / 2;

    // workspace carve-out (256B aligned)
    char* ws = (char*)d_ws;
    size_t off = 0;
    auto alloc = [&](size_t bytes) -> void* {
        void* p = ws + off;
        off = (off + bytes + 255) & ~(size_t)255;
        return p;
    };
    float*    dinv      = (float*)   alloc((size_t)NN * 4);
    int*      superCnt  = (int*)     alloc(128 * 4);
    unsigned* superArr  = (unsigned*)alloc((size_t)NSUP * PAD * 4);   // 9.6 MB padded
    int*      rowptr    = (int*)     alloc((size_t)(NN + 1) * 4);
    unsigned* esrc      = (unsigned*)alloc((size_t)E * 4);            // 4 B payload
    uint2*    xh        = (uint2*)   alloc((size_t)NN * 16 * 8);      // fp16 xs
    __half*   bufAh     = (__half*)  alloc((size_t)NN * F * 2);       // fp16 conv out
    __half*   bufBh     = (__half*)  alloc((size_t)NN * F * 2);       // fp16 lin1 out

    hipMemsetAsync(superCnt, 0, 128 * 4, stream);

    binA_direct_kernel<<<(E + ACHUNK - 1) / ACHUNK, 256, 0, stream>>>(
        ei, superCnt, superArr, E);
    binB_fused_kernel<<<NSUP, 1024, 0, stream>>>(
        superArr, superCnt, rowptr, dinv, esrc, E);

    // xs = fp16(x * dinv[row])  (conv1 gather operand; needs dinv)
    f2h_scale_kernel<<<(NN * 16 + 255) / 256, 256, 0, stream>>>(
        (const float4*)x, dinv, xh, NN * 16);

    const int conv_blocks = (NN + 3) / 4;     // wave per row, 4 waves/block
    const int lin_blocks = (NN + 63) / 64;    // 1563

    // conv1: xs -> bufAh (true conv1 output, fp16)
    conv_ps_kernel<<<conv_blocks, 256, 0, stream>>>(xh, rowptr, esrc, dinv,
                                                    (uint2*)bufAh, NN);

    // lin1: relu(bufAh) @ W1 + b1, relu, * dinv -> bufBh (fp16, prescaled)
    lin1_kernel<<<lin_blocks, 256, 0, stream>>>((const uint2*)bufAh, W1, b1, dinv,
                                                bufBh, NN);

    // conv2: bufBh -> bufAh (true conv2 output, fp16)
    conv_ps_kernel<<<conv_blocks, 256, 0, stream>>>((const uint2*)bufBh, rowptr, esrc,
                                                    dinv, (uint2*)bufAh, NN);

    // lin2 + log_softmax
    lin2_kernel<<<lin_blocks, 256, 0, stream>>>((const uint2*)bufAh, W2, b2, out, NN);
}

// Round 13
// 180.009 us; speedup vs baseline: 8.7938x; 1.0059x over previous
//
#include <hip/hip_runtime.h>
#include <hip/hip_fp16.h>
#include <math.h>

#define NN 100000
#define F 64
#define NC 47
#define NSUP 391       // ceil(NN/256) super-bins
#define SUPR 256       // rows per super-bin
#define ACHUNK 4096    // edges per binA_direct block (LDS int2 stash = 32 KB)
#define PAD 5120       // padded bucket capacity per super (mean 4096, sd ~64, +16 sigma)

// ---------------------------------------------------------------------------
// binA_direct: single pass over ei (dtype detected per-block by wave 0's
// ballot over the first 64 odd words). Per 4096-edge chunk: LDS-stash (s,d),
// LDS histogram by super (dst>>8), reserve a contiguous segment in the
// super's PADDED bucket via one atomicAdd per (block,super), write payload
// src|dstLocal<<17 directly. 391 bucket tails = 25 KB hot lines ->
// L2-resident -> ~1x write amplification. (round-11/12 proven structure)
// ---------------------------------------------------------------------------
__global__ __launch_bounds__(256) void binA_direct_kernel(const void* __restrict__ ei,
                                                          int* __restrict__ superCnt,
                                                          unsigned* __restrict__ superArr,
                                                          int E) {
    __shared__ int2 ed[ACHUNK];          // 32 KB
    __shared__ int h[512], gbase[512];
    __shared__ int is64_s;
    int t = threadIdx.x;
    if (t < 64) {
        int v = ((const int*)ei)[2 * t + 1];
        unsigned long long ball = __ballot(v == 0);
        if (t == 0) is64_s = (ball == ~0ULL) ? 1 : 0;   // all-zero odd words => int64
    }
    h[t] = 0; h[t + 256] = 0;
    __syncthreads();
    bool is64 = (is64_s != 0);
    int cb = blockIdx.x * ACHUNK;
    int ce = min(cb + ACHUNK, E);
    for (int i = cb + t; i < ce; i += 256) {
        int s, d;
        if (is64) {
            s = (int)((const long long*)ei)[i];
            d = (int)((const long long*)ei)[(size_t)E + i];
        } else {
            s = ((const int*)ei)[i];
            d = ((const int*)ei)[(size_t)E + i];
        }
        ed[i - cb] = make_int2(s, d);
        atomicAdd(&h[d >> 8], 1);
    }
    __syncthreads();
    for (int b = t; b < 512; b += 256) {
        int c = h[b];
        gbase[b] = (b < NSUP && c > 0) ? atomicAdd(&superCnt[b], c) : 0;
        h[b] = 0;                         // reuse as local cursor
    }
    __syncthreads();
    int nloc = ce - cb;
    for (int i = t; i < nloc; i += 256) {
        int2 e = ed[i];
        int sup = e.y >> 8;
        int pos = atomicAdd(&h[sup], 1);
        unsigned pk = (unsigned)e.x | ((unsigned)(e.y & (SUPR - 1)) << 17);
        superArr[(size_t)sup * PAD + gbase[sup] + pos] = pk;
    }
}

// ---------------------------------------------------------------------------
// superscan: exclusive scan of superCnt (391) -> superBase[0..391].
// One tiny block; removes the per-block serial walk binB used to do.
// ---------------------------------------------------------------------------
__global__ __launch_bounds__(512) void superscan_kernel(const int* __restrict__ superCnt,
                                                        int* __restrict__ superBase) {
    __shared__ int sc[512];
    int t = threadIdx.x;
    int v = (t < NSUP) ? superCnt[t] : 0;
    sc[t] = v;
    __syncthreads();
    for (int off = 1; off < 512; off <<= 1) {
        int a = (t >= off) ? sc[t - off] : 0;
        __syncthreads();
        sc[t] += a;
        __syncthreads();
    }
    if (t < NSUP) superBase[t] = sc[t] - v;
    if (t == NSUP - 1) superBase[NSUP] = sc[t];   // == E
}

// ---------------------------------------------------------------------------
// binB: one 256-thread block per super (391 blocks -> full CU coverage).
// LDS histogram of the 256 local rows (= in-degree, privatized), WAVE-level
// scan (shfl_up intra-wave, 4-entry cross-wave fixup; 4 barriers vs 20),
// -> rowptr + dinv, then rank-and-place src indices into compact esrc.
// ---------------------------------------------------------------------------
__global__ __launch_bounds__(256) void binB_kernel(const unsigned* __restrict__ superArr,
                                                   const int* __restrict__ superCnt,
                                                   const int* __restrict__ superBase,
                                                   int* __restrict__ rowptr,
                                                   float* __restrict__ dinv,
                                                   unsigned* __restrict__ esrc, int E) {
    __shared__ int hist[256];
    __shared__ int cur[256];
    __shared__ int wsum[4], wbase[4];
    int s = blockIdx.x, t = threadIdx.x;
    int wb = superBase[s];
    int cnt = superCnt[s];
    const unsigned* arr = superArr + (size_t)s * PAD;
    hist[t] = 0;
    __syncthreads();
    for (int i = t; i < cnt; i += 256)
        atomicAdd(&hist[(arr[i] >> 17) & (SUPR - 1)], 1);
    __syncthreads();
    int myv = hist[t];
    int lane = t & 63, w = t >> 6;
    int v = myv;
#pragma unroll
    for (int off = 1; off < 64; off <<= 1) {
        int u = __shfl_up(v, off, 64);
        if (lane >= off) v += u;
    }
    if (lane == 63) wsum[w] = v;
    __syncthreads();
    if (t == 0) {
        int r = 0;
#pragma unroll
        for (int j = 0; j < 4; ++j) { wbase[j] = r; r += wsum[j]; }
    }
    __syncthreads();
    int excl = v + wbase[w] - myv;       // exclusive prefix of row t within super
    int gr = s * SUPR + t;
    if (gr < NN) {
        rowptr[gr] = wb + excl;
        dinv[gr] = (myv > 0) ? rsqrtf((float)myv) : 0.0f;
    }
    if (s == NSUP - 1 && t == 0) rowptr[NN] = E;
    cur[t] = excl;
    __syncthreads();
    for (int i = t; i < cnt; i += 256) {
        unsigned e = arr[i];
        int r = (e >> 17) & (SUPR - 1);
        int pos = atomicAdd(&cur[r], 1);
        esrc[wb + pos] = e & 0x1FFFFu;
    }
}

// ---------------------------------------------------------------------------
// f2h_scale: xs[r][:] = fp16(x[r][:] * dinv[r])  (prescale by src-side dinv)
// ---------------------------------------------------------------------------
__global__ void f2h_scale_kernel(const float4* __restrict__ in4,
                                 const float* __restrict__ dinv,
                                 uint2* __restrict__ outh, int n4) {
    int i = blockIdx.x * blockDim.x + threadIdx.x;
    if (i >= n4) return;
    float dv = dinv[i >> 4];
    float4 v = in4[i];
    __half2 h01 = __floats2half2_rn(v.x * dv, v.y * dv);
    __half2 h23 = __floats2half2_rn(v.z * dv, v.w * dv);
    uint2 r;
    r.x = *(const unsigned*)&h01;
    r.y = *(const unsigned*)&h23;
    outh[i] = r;
}

// ---------------------------------------------------------------------------
// conv: wave per row, prescaled fp16 gather operand, 4 B edge payload,
// 4-deep gather issue. out[row] = fp16(dinv[row] * sum_e xs[src_e]).
// (round-12 proven, byte-identical)
// ---------------------------------------------------------------------------
__global__ __launch_bounds__(256) void conv_ps_kernel(const uint2* __restrict__ xh,
                                                      const int* __restrict__ rowptr,
                                                      const unsigned* __restrict__ esrc,
                                                      const float* __restrict__ dinv,
                                                      uint2* __restrict__ outh, int n) {
    int row = blockIdx.x * 4 + (threadIdx.x >> 6);
    if (row >= n) return;
    int lane = threadIdx.x & 63;
    int es = lane >> 4, f4 = lane & 15;
    int beg = rowptr[row], end = rowptr[row + 1];
    float4 acc = make_float4(0.f, 0.f, 0.f, 0.f);
    for (int base = beg; base < end; base += 64) {
        int m = end - base;
        if (m > 64) m = 64;
        int pk = (lane < m) ? (int)esrc[base + lane] : 0;
        int iters = (m + 3) >> 2;
        int k = 0;
        for (; k + 4 <= iters; k += 4) {
            int i0 = 4 * k + es, i1 = i0 + 4, i2 = i0 + 8, i3 = i0 + 12;
            int s0 = __shfl(pk, i0, 64);
            int s1 = __shfl(pk, i1, 64);
            int s2 = __shfl(pk, i2, 64);
            int s3 = __shfl(pk, i3, 64);
            float w0 = (i0 < m) ? 1.0f : 0.0f;
            float w1 = (i1 < m) ? 1.0f : 0.0f;
            float w2 = (i2 < m) ? 1.0f : 0.0f;
            float w3 = (i3 < m) ? 1.0f : 0.0f;
            uint2 v0 = xh[(size_t)s0 * 16 + f4];
            uint2 v1 = xh[(size_t)s1 * 16 + f4];
            uint2 v2 = xh[(size_t)s2 * 16 + f4];
            uint2 v3 = xh[(size_t)s3 * 16 + f4];
            float2 a01 = __half22float2(*reinterpret_cast<const __half2*>(&v0.x));
            float2 a23 = __half22float2(*reinterpret_cast<const __half2*>(&v0.y));
            acc.x = fmaf(a01.x, w0, acc.x); acc.y = fmaf(a01.y, w0, acc.y);
            acc.z = fmaf(a23.x, w0, acc.z); acc.w = fmaf(a23.y, w0, acc.w);
            float2 b01 = __half22float2(*reinterpret_cast<const __half2*>(&v1.x));
            float2 b23 = __half22float2(*reinterpret_cast<const __half2*>(&v1.y));
            acc.x = fmaf(b01.x, w1, acc.x); acc.y = fmaf(b01.y, w1, acc.y);
            acc.z = fmaf(b23.x, w1, acc.z); acc.w = fmaf(b23.y, w1, acc.w);
            float2 c01 = __half22float2(*reinterpret_cast<const __half2*>(&v2.x));
            float2 c23 = __half22float2(*reinterpret_cast<const __half2*>(&v2.y));
            acc.x = fmaf(c01.x, w2, acc.x); acc.y = fmaf(c01.y, w2, acc.y);
            acc.z = fmaf(c23.x, w2, acc.z); acc.w = fmaf(c23.y, w2, acc.w);
            float2 d01 = __half22float2(*reinterpret_cast<const __half2*>(&v3.x));
            float2 d23 = __half22float2(*reinterpret_cast<const __half2*>(&v3.y));
            acc.x = fmaf(d01.x, w3, acc.x); acc.y = fmaf(d01.y, w3, acc.y);
            acc.z = fmaf(d23.x, w3, acc.z); acc.w = fmaf(d23.y, w3, acc.w);
        }
        for (; k < iters; ++k) {
            int i0 = 4 * k + es;
            int s0 = __shfl(pk, i0, 64);
            float w0 = (i0 < m) ? 1.0f : 0.0f;
            uint2 v0 = xh[(size_t)s0 * 16 + f4];
            float2 a01 = __half22float2(*reinterpret_cast<const __half2*>(&v0.x));
            float2 a23 = __half22float2(*reinterpret_cast<const __half2*>(&v0.y));
            acc.x = fmaf(a01.x, w0, acc.x); acc.y = fmaf(a01.y, w0, acc.y);
            acc.z = fmaf(a23.x, w0, acc.z); acc.w = fmaf(a23.y, w0, acc.w);
        }
    }
#pragma unroll
    for (int off = 16; off <= 32; off <<= 1) {
        acc.x += __shfl_xor(acc.x, off, 64);
        acc.y += __shfl_xor(acc.y, off, 64);
        acc.z += __shfl_xor(acc.z, off, 64);
        acc.w += __shfl_xor(acc.w, off, 64);
    }
    if (es == 0) {
        float dv = dinv[row];
        __half2 h01 = __floats2half2_rn(acc.x * dv, acc.y * dv);
        __half2 h23 = __floats2half2_rn(acc.z * dv, acc.w * dv);
        uint2 r;
        r.x = *(const unsigned*)&h01;
        r.y = *(const unsigned*)&h23;
        outh[(size_t)row * 16 + f4] = r;
    }
}

// ---------------------------------------------------------------------------
// Register-tiled lin kernels (round-12 proven, byte-identical).
// ---------------------------------------------------------------------------
__device__ __forceinline__ float4 h4_to_f4_relu(uint2 hv) {
    float2 a01 = __half22float2(*reinterpret_cast<const __half2*>(&hv.x));
    float2 a23 = __half22float2(*reinterpret_cast<const __half2*>(&hv.y));
    return make_float4(fmaxf(a01.x, 0.f), fmaxf(a01.y, 0.f),
                       fmaxf(a23.x, 0.f), fmaxf(a23.y, 0.f));
}

__global__ __launch_bounds__(256) void lin1_kernel(const uint2* __restrict__ h2,
                                                   const float* __restrict__ W1,
                                                   const float* __restrict__ b1,
                                                   const float* __restrict__ dinv,
                                                   __half* __restrict__ outh, int n) {
    __shared__ float wt[64 * 64];
    __shared__ float ht[64 * 64];
    int t = threadIdx.x;
    for (int i = t; i < 64 * 64; i += 256) {
        int k = i >> 6, c = i & 63;
        int kq = k >> 2, slot = kq ^ (c & 7);
        wt[c * 64 + slot * 4 + (k & 3)] = W1[i];
    }
    int row0 = blockIdx.x * 64;
    float4* ht4 = (float4*)ht;
#pragma unroll
    for (int j = 0; j < 4; ++j) {
        int flat = t + 256 * j;
        int r = flat >> 4;
        int kq = flat & 15;
        int gr = row0 + r;
        float4 v = (gr < n) ? h4_to_f4_relu(h2[(size_t)gr * 16 + kq])
                            : make_float4(0.f, 0.f, 0.f, 0.f);
        ht4[r * 16 + (kq ^ ((r >> 2) & 7))] = v;
    }
    __syncthreads();
    const float4* wt4 = (const float4*)wt;
    const float4* ht4c = (const float4*)ht;

    int tx = t & 15, ty = t >> 4;
    float acc[4][4] = {};
#pragma unroll 2
    for (int kq = 0; kq < 16; ++kq) {
        int wslot = kq ^ (tx & 7);
        float4 b0 = wt4[(tx +  0) * 16 + wslot];
        float4 b1v = wt4[(tx + 16) * 16 + wslot];
        float4 b2v = wt4[(tx + 32) * 16 + wslot];
        float4 b3v = wt4[(tx + 48) * 16 + wslot];
        int aslot = kq ^ (ty & 7);
#pragma unroll
        for (int i = 0; i < 4; ++i) {
            float4 a = ht4c[(4 * ty + i) * 16 + aslot];
            acc[i][0] = fmaf(a.x, b0.x,  fmaf(a.y, b0.y,  fmaf(a.z, b0.z,  fmaf(a.w, b0.w,  acc[i][0]))));
            acc[i][1] = fmaf(a.x, b1v.x, fmaf(a.y, b1v.y, fmaf(a.z, b1v.z, fmaf(a.w, b1v.w, acc[i][1]))));
            acc[i][2] = fmaf(a.x, b2v.x, fmaf(a.y, b2v.y, fmaf(a.z, b2v.z, fmaf(a.w, b2v.w, acc[i][2]))));
            acc[i][3] = fmaf(a.x, b3v.x, fmaf(a.y, b3v.y, fmaf(a.z, b3v.z, fmaf(a.w, b3v.w, acc[i][3]))));
        }
    }
    float bj[4];
#pragma unroll
    for (int g = 0; g < 4; ++g) bj[g] = b1[tx + 16 * g];
    int r0 = row0 + 4 * ty;
#pragma unroll
    for (int i = 0; i < 4; ++i) {
        int r = r0 + i;
        if (r >= n) break;
        float dv = dinv[r];
#pragma unroll
        for (int g = 0; g < 4; ++g)
            outh[(size_t)r * 64 + tx + 16 * g] =
                __float2half(fmaxf(acc[i][g] + bj[g], 0.0f) * dv);
    }
}

__global__ __launch_bounds__(256) void lin2_kernel(const uint2* __restrict__ h2,
                                                   const float* __restrict__ W2,
                                                   const float* __restrict__ b2,
                                                   float* __restrict__ out, int n) {
    __shared__ float wt[64 * 64];   // cols >= 47 zero-padded
    __shared__ float ht[64 * 64];
    int t = threadIdx.x;
    for (int i = t; i < 64 * 64; i += 256) {
        int k = i >> 6, c = i & 63;
        int kq = k >> 2, slot = kq ^ (c & 7);
        wt[c * 64 + slot * 4 + (k & 3)] = (c < NC) ? W2[k * NC + c] : 0.0f;
    }
    int row0 = blockIdx.x * 64;
    float4* ht4 = (float4*)ht;
#pragma unroll
    for (int j = 0; j < 4; ++j) {
        int flat = t + 256 * j;
        int r = flat >> 4;
        int kq = flat & 15;
        int gr = row0 + r;
        float4 v = (gr < n) ? h4_to_f4_relu(h2[(size_t)gr * 16 + kq])
                            : make_float4(0.f, 0.f, 0.f, 0.f);
        ht4[r * 16 + (kq ^ ((r >> 2) & 7))] = v;
    }
    __syncthreads();
    const float4* wt4 = (const float4*)wt;
    const float4* ht4c = (const float4*)ht;

    int tx = t & 15, ty = t >> 4;
    float acc[4][4] = {};
#pragma unroll 2
    for (int kq = 0; kq < 16; ++kq) {
        int wslot = kq ^ (tx & 7);
        float4 b0 = wt4[(tx +  0) * 16 + wslot];
        float4 b1v = wt4[(tx + 16) * 16 + wslot];
        float4 b2v = wt4[(tx + 32) * 16 + wslot];
        float4 b3v = wt4[(tx + 48) * 16 + wslot];
        int aslot = kq ^ (ty & 7);
#pragma unroll
        for (int i = 0; i < 4; ++i) {
            float4 a = ht4c[(4 * ty + i) * 16 + aslot];
            acc[i][0] = fmaf(a.x, b0.x,  fmaf(a.y, b0.y,  fmaf(a.z, b0.z,  fmaf(a.w, b0.w,  acc[i][0]))));
            acc[i][1] = fmaf(a.x, b1v.x, fmaf(a.y, b1v.y, fmaf(a.z, b1v.z, fmaf(a.w, b1v.w, acc[i][1]))));
            acc[i][2] = fmaf(a.x, b2v.x, fmaf(a.y, b2v.y, fmaf(a.z, b2v.z, fmaf(a.w, b2v.w, acc[i][2]))));
            acc[i][3] = fmaf(a.x, b3v.x, fmaf(a.y, b3v.y, fmaf(a.z, b3v.z, fmaf(a.w, b3v.w, acc[i][3]))));
        }
    }
    bool vm[4];
    float bj[4];
#pragma unroll
    for (int g = 0; g < 4; ++g) {
        int c = tx + 16 * g;
        vm[g] = (c < NC);
        bj[g] = vm[g] ? b2[c] : 0.0f;
    }
    int r0 = row0 + 4 * ty;
#pragma unroll
    for (int i = 0; i < 4; ++i) {
        int r = r0 + i;
        float v[4];
        float m = -INFINITY;
#pragma unroll
        for (int g = 0; g < 4; ++g) {
            v[g] = acc[i][g] + bj[g];
            if (vm[g]) m = fmaxf(m, v[g]);
        }
#pragma unroll
        for (int off = 8; off > 0; off >>= 1) m = fmaxf(m, __shfl_xor(m, off, 64));
        float s = 0.0f;
#pragma unroll
        for (int g = 0; g < 4; ++g)
            if (vm[g]) s += expf(v[g] - m);
#pragma unroll
        for (int off = 8; off > 0; off >>= 1) s += __shfl_xor(s, off, 64);
        float lse = m + logf(s);
        if (r < n) {
#pragma unroll
            for (int g = 0; g < 4; ++g)
                if (vm[g]) out[(size_t)r * NC + tx + 16 * g] = v[g] - lse;
        }
    }
}

// ---------------------------------------------------------------------------
extern "C" void kernel_launch(void* const* d_in, const int* in_sizes, int n_in,
                              void* d_out, int out_size, void* d_ws, size_t ws_size,
                              hipStream_t stream) {
    const float* x  = (const float*)d_in[0];
    const void*  ei = d_in[1];
    const float* W1 = (const float*)d_in[2];
    const float* b1 = (const float*)d_in[3];
    const float* W2 = (const float*)d_in[4];
    const float* b2 = (const float*)d_in[5];
    float* out = (float*)d_out;

    const int E = in_sizes[1] / 2;

    // workspace carve-out (256B aligned)
    char* ws = (char*)d_ws;
    size_t off = 0;
    auto alloc = [&](size_t bytes) -> void* {
        void* p = ws + off;
        off = (off + bytes + 255) & ~(size_t)255;
        return p;
    };
    float*    dinv      = (float*)   alloc((size_t)NN * 4);
    int*      superCnt  = (int*)     alloc(512 * 4);
    int*      superBase = (int*)     alloc(512 * 4);
    unsigned* superArr  = (unsigned*)alloc((size_t)NSUP * PAD * 4);   // 8.0 MB padded
    int*      rowptr    = (int*)     alloc((size_t)(NN + 1) * 4);
    unsigned* esrc      = (unsigned*)alloc((size_t)E * 4);            // 4 B payload
    uint2*    xh        = (uint2*)   alloc((size_t)NN * 16 * 8);      // fp16 xs
    __half*   bufAh     = (__half*)  alloc((size_t)NN * F * 2);       // fp16 conv out
    __half*   bufBh     = (__half*)  alloc((size_t)NN * F * 2);       // fp16 lin1 out

    hipMemsetAsync(superCnt, 0, 512 * 4, stream);

    binA_direct_kernel<<<(E + ACHUNK - 1) / ACHUNK, 256, 0, stream>>>(
        ei, superCnt, superArr, E);
    superscan_kernel<<<1, 512, 0, stream>>>(superCnt, superBase);
    binB_kernel<<<NSUP, 256, 0, stream>>>(
        superArr, superCnt, superBase, rowptr, dinv, esrc, E);

    // xs = fp16(x * dinv[row])  (conv1 gather operand; needs dinv)
    f2h_scale_kernel<<<(NN * 16 + 255) / 256, 256, 0, stream>>>(
        (const float4*)x, dinv, xh, NN * 16);

    const int conv_blocks = (NN + 3) / 4;     // wave per row, 4 waves/block
    const int lin_blocks = (NN + 63) / 64;    // 1563

    // conv1: xs -> bufAh (true conv1 output, fp16)
    conv_ps_kernel<<<conv_blocks, 256, 0, stream>>>(xh, rowptr, esrc, dinv,
                                                    (uint2*)bufAh, NN);

    // lin1: relu(bufAh) @ W1 + b1, relu, * dinv -> bufBh (fp16, prescaled)
    lin1_kernel<<<lin_blocks, 256, 0, stream>>>((const uint2*)bufAh, W1, b1, dinv,
                                                bufBh, NN);

    // conv2: bufBh -> bufAh (true conv2 output, fp16)
    conv_ps_kernel<<<conv_blocks, 256, 0, stream>>>((const uint2*)bufBh, rowptr, esrc,
                                                    dinv, (uint2*)bufAh, NN);

    // lin2 + log_softmax
    lin2_kernel<<<lin_blocks, 256, 0, stream>>>((const uint2*)bufAh, W2, b2, out, NN);
}